// Round 6
// baseline (582.961 us; speedup 1.0000x reference)
//
#include <hip/hip_runtime.h>
#include <hip/hip_bf16.h>
#include <hip/hip_fp16.h>

#define N_NODES 50000
#define F_IN    64
#define HDIM    256
#define E_EDGES 800000
#define G_GRAPHS 2048
#define L_LAYERS 4
#define T_OUT   4
#define BN_EPS  1e-5f

#define NPAD    50176   // 196 * 256
#define NBLK    196
#define LDK     264     // fp16 LDS row stride for K=256 tiles
#define SLICES  8       // feature slices (one per XCD); 32 fp16 = 64B each
#define AGG_BLK ((N_NODES + 63) / 64)   // 64 nodes per block (4 waves x 16)

// Wt buffer offsets (fp16 elements)
#define WT_CONV 0
#define WT_PROJ 262144
#define WT_H1   278528
#define WT_H2   409600
#define WT_TOT  442368

typedef _Float16 half8 __attribute__((ext_vector_type(8)));
typedef float    f32x4 __attribute__((ext_vector_type(4)));
typedef unsigned int u32x4 __attribute__((ext_vector_type(4)));

// ---- degree count + weight transposes + BN precompute + zero rows ----------
__global__ void k_deg_wcvt(const int* __restrict__ dst, int* __restrict__ cnt,
                           const float* __restrict__ convW, const float* __restrict__ projW,
                           const float* __restrict__ W1, const float* __restrict__ W2,
                           _Float16* __restrict__ Wt,
                           const float* __restrict__ convb, const float* __restrict__ gamma,
                           const float* __restrict__ beta, const float* __restrict__ mean,
                           const float* __restrict__ var, float* __restrict__ bnp,
                           ushort* __restrict__ Wh) {
    int i = blockIdx.x * 256 + threadIdx.x;
    if (i < E_EDGES) atomicAdd(&cnt[dst[i]], 1);
    if (i < 262144) {                       // conv: 4 x [256x256]
        int l = i >> 16, r = i & 65535;
        int k = r >> 8, n = r & 255;
        Wt[WT_CONV + (size_t)l * 65536 + n * 256 + k] = (_Float16)convW[(size_t)l * 65536 + k * 256 + n];
        return;
    }
    int j = i - 262144;
    if (j >= 0 && j < 16384) {              // proj: [64x256] -> [256][64]
        int k = j >> 8, n = j & 255;
        Wt[WT_PROJ + n * 64 + k] = (_Float16)projW[k * 256 + n];
        return;
    }
    j -= 16384;
    if (j >= 0 && j < 131072) {             // W1: [512x256] -> [256][512]
        int k = j >> 8, n = j & 255;
        Wt[WT_H1 + n * 512 + k] = (_Float16)W1[k * 256 + n];
        return;
    }
    j -= 131072;
    if (j >= 0 && j < 32768) {              // W2: [256x128] -> [128][256]
        int k = j >> 7, n = j & 127;
        Wt[WT_H2 + n * 256 + k] = (_Float16)W2[k * 128 + n];
        return;
    }
    j -= 32768;
    if (j >= 0 && j < L_LAYERS * HDIM) {    // BN: scale = g*rsqrt(v+eps), shift = (cb-m)*scale+b
        float scv = gamma[j] * rsqrtf(var[j] + BN_EPS);
        bnp[j] = scv;
        bnp[L_LAYERS * HDIM + j] = (convb[j] - mean[j]) * scv + beta[j];
        return;
    }
    j -= L_LAYERS * HDIM;
    if (j >= 0 && j < SLICES * 32) {        // zero row (idx N_NODES) in each slice of hWh
        int sl = j >> 5, w = j & 31;
        Wh[((size_t)sl * NPAD + N_NODES) * 32 + w] = 0;
    }
}

// ---- scan pass 1: per-block inclusive scan ---------------------------------
__global__ void k_scan1(const int* __restrict__ cnt, int* __restrict__ iscan,
                        int* __restrict__ bsum) {
    __shared__ int sm[256];
    int t = threadIdx.x, i = blockIdx.x * 256 + t;
    sm[t] = cnt[i];
    __syncthreads();
    for (int off = 1; off < 256; off <<= 1) {
        int u = (t >= off) ? sm[t - off] : 0;
        __syncthreads();
        sm[t] += u;
        __syncthreads();
    }
    iscan[i] = sm[t];
    if (t == 255) bsum[blockIdx.x] = sm[255];
}

// ---- scan pass 2: block offset computed locally + emit rowptr/wpos/inv -----
__global__ void k_scan23(const int* __restrict__ cnt, const int* __restrict__ iscan,
                         const int* __restrict__ bsum, int* __restrict__ rowptr,
                         int* __restrict__ wpos, float* __restrict__ inv) {
    __shared__ int sm[256];
    int t = threadIdx.x;
    int b = blockIdx.x;
    sm[t] = (t < b) ? bsum[t] : 0;   // t < b <= 195 < NBLK
    __syncthreads();
    for (int off = 128; off > 0; off >>= 1) {
        if (t < off) sm[t] += sm[t + off];
        __syncthreads();
    }
    int boff = sm[0];
    int i = b * 256 + t;
    int c = cnt[i];
    int excl = boff + iscan[i] - c;
    rowptr[i] = excl;
    wpos[i] = excl;
    inv[i] = rsqrtf((float)c + 1.0f);
}

// ---- scatter edges into CSR order (src ids fit in ushort: N < 65536) -------
__global__ void k_scatter(const int* __restrict__ ei, int* __restrict__ wpos,
                          ushort* __restrict__ csr_src) {
    int e = blockIdx.x * blockDim.x + threadIdx.x;
    if (e < E_EDGES) {
        int s = ei[e];
        int d = ei[E_EDGES + e];
        int pos = atomicAdd(&wpos[d], 1);
        csr_src[pos] = (ushort)s;
    }
}

// ---- proj GEMM via MFMA: h16 = fp16(relu(x @ Wp + b)), slice-major out -----
__global__ __launch_bounds__(256) void k_proj_mfma(const float* __restrict__ x,
                                                   const _Float16* __restrict__ Wpt,
                                                   const float* __restrict__ bias,
                                                   ushort* __restrict__ h16, int nrows) {
    __shared__ _Float16 hs[64 * 72];
    int block_r = blockIdx.x * 64;
    for (int i = threadIdx.x; i < 64 * 16; i += 256) {
        int row = i >> 4;
        int c4 = (i & 15) * 4;
        float4 v = (block_r + row < nrows)
                       ? *(const float4*)(x + (size_t)(block_r + row) * F_IN + c4)
                       : make_float4(0.f, 0.f, 0.f, 0.f);
        _Float16* p = &hs[row * 72 + c4];
        p[0] = (_Float16)v.x; p[1] = (_Float16)v.y;
        p[2] = (_Float16)v.z; p[3] = (_Float16)v.w;
    }
    __syncthreads();

    int wave = threadIdx.x >> 6;
    int lane = threadIdx.x & 63;
    int l16 = lane & 15;
    int quad = lane >> 4;
    int n0 = wave * 64;

    f32x4 acc[4][4] = {};
#pragma unroll
    for (int k0 = 0; k0 < F_IN; k0 += 32) {
        half8 a[4], b[4];
#pragma unroll
        for (int ai = 0; ai < 4; ai++)
            a[ai] = *(const half8*)&hs[(ai * 16 + l16) * 72 + k0 + quad * 8];
#pragma unroll
        for (int bj = 0; bj < 4; bj++)
            b[bj] = *(const half8*)&Wpt[(size_t)(n0 + bj * 16 + l16) * F_IN + k0 + quad * 8];
#pragma unroll
        for (int ai = 0; ai < 4; ai++)
#pragma unroll
            for (int bj = 0; bj < 4; bj++)
                acc[ai][bj] = __builtin_amdgcn_mfma_f32_16x16x32_f16(a[ai], b[bj], acc[ai][bj], 0, 0, 0);
    }

#pragma unroll
    for (int ai = 0; ai < 4; ai++) {
        int rowb = block_r + ai * 16 + quad * 4;
#pragma unroll
        for (int r = 0; r < 4; r++) {
            int row = rowb + r;
            if (row >= nrows) continue;
#pragma unroll
            for (int bj = 0; bj < 4; bj++) {
                int col = n0 + bj * 16 + l16;
                float v = fmaxf(acc[ai][bj][r] + bias[col], 0.f);
                h16[((size_t)(col >> 5) * NPAD + row) * 32 + (col & 31)] = __half_as_ushort(__float2half(v));
            }
        }
    }
}

// ---- conv GEMM via MFMA: hWh = fp16((h16 @ W) * inv[row]), slice-major -----
__global__ __launch_bounds__(256) void k_gemm_mfma(const ushort* __restrict__ h16,
                                                   const _Float16* __restrict__ Wt,
                                                   const float* __restrict__ inv,
                                                   _Float16* __restrict__ outh, int nrows) {
    __shared__ _Float16 hs[64 * LDK];
    int block_r = blockIdx.x * 64;
    for (int i = threadIdx.x; i < 64 * 32; i += 256) {
        int row = i >> 5;
        int q = i & 31;             // slice = q>>2, 16B granule = q&3
        uint4 v;
        if (block_r + row < nrows)
            v = *(const uint4*)(h16 + ((size_t)(q >> 2) * NPAD + block_r + row) * 32 + (q & 3) * 8);
        else
            v = make_uint4(0u, 0u, 0u, 0u);
        *(uint4*)&hs[row * LDK + q * 8] = v;
    }
    __syncthreads();

    int wave = threadIdx.x >> 6;
    int lane = threadIdx.x & 63;
    int l16 = lane & 15;
    int quad = lane >> 4;
    int n0 = wave * 64;

    f32x4 acc[4][4] = {};
    for (int k0 = 0; k0 < HDIM; k0 += 32) {
        half8 a[4], b[4];
#pragma unroll
        for (int ai = 0; ai < 4; ai++)
            a[ai] = *(const half8*)&hs[(ai * 16 + l16) * LDK + k0 + quad * 8];
#pragma unroll
        for (int bj = 0; bj < 4; bj++)
            b[bj] = *(const half8*)&Wt[(size_t)(n0 + bj * 16 + l16) * HDIM + k0 + quad * 8];
#pragma unroll
        for (int ai = 0; ai < 4; ai++)
#pragma unroll
            for (int bj = 0; bj < 4; bj++)
                acc[ai][bj] = __builtin_amdgcn_mfma_f32_16x16x32_f16(a[ai], b[bj], acc[ai][bj], 0, 0, 0);
    }

#pragma unroll
    for (int ai = 0; ai < 4; ai++) {
        int rowb = block_r + ai * 16 + quad * 4;
#pragma unroll
        for (int r = 0; r < 4; r++) {
            int row = rowb + r;
            if (row >= nrows) continue;
            float sc = inv[row];
#pragma unroll
            for (int bj = 0; bj < 4; bj++) {
                int col = n0 + bj * 16 + l16;
                outh[((size_t)(col >> 5) * NPAD + row) * 32 + (col & 31)] = (_Float16)(acc[ai][bj][r] * sc);
            }
        }
    }
}

// ---- fused CSR aggregation, feature-sliced across XCDs ---------------------
// blockIdx % 8 = feature slice (64B of the 512B row) -> one XCD; per-XCD table
// working set = 3.2MB ~ L2. Each wave owns 16 nodes (4 groups of 4) so the
// per-wave fixed cost (rowptr/csr/self/res/inv loads, BN, reduce, store) is
// amortized 4x; all group state is loaded upfront as independent requests and
// pipelines behind the first group's gather compute. BN hoisted (slice-unif).
__global__ __launch_bounds__(256) void k_aggr(const int* __restrict__ rowptr,
                                              const ushort* __restrict__ csr,
                                              const ushort* __restrict__ hWh,
                                              const float* __restrict__ inv,
                                              const float* __restrict__ bnscale,
                                              const float* __restrict__ bnshift,
                                              ushort* __restrict__ h16) {
    int slice = blockIdx.x & 7;
    int blk = blockIdx.x >> 3;
    int lane = threadIdx.x & 63;
    int wv = threadIdx.x >> 6;
    int nb = lane >> 4;            // node sub 0..3 within group
    int g  = (lane >> 2) & 3;      // edge slot / half2-pair 0..3
    int f  = lane & 3;             // 16B granule 0..3
    int l15 = lane & 15;
    int nbase = blk * 64 + wv * 16;            // wave's 16 nodes

    const uint4* tbl = (const uint4*)hWh + (size_t)slice * (NPAD * 4);
    const unsigned* tbl_w = (const unsigned*)tbl;
    const unsigned* h16_w = (const unsigned*)h16 + (size_t)slice * (NPAD * 16);
    unsigned fg4 = (unsigned)(f * 4 + g);

    // hoisted BN constants (slice-uniform for this lane's half2 pair)
    int c0f = slice * 32 + f * 8 + g * 2;
    float2 scl = *(const float2*)(bnscale + c0f);
    float2 shf = *(const float2*)(bnshift + c0f);

    // ---- upfront loads for all 4 groups (independent, deep MLP) ----
    int nodeA[4], begA[4], mA[4], mmA[4];
    int idxA[4][4];
    unsigned selfA[4], resA[4], eoffA[4];
    float ivA[4];

#define LOADG(gr)                                                              \
    {                                                                          \
        int node = nbase + (gr) * 4 + nb;                                      \
        nodeA[gr] = node;                                                      \
        int b0 = rowptr[node];                                                 \
        int b1 = rowptr[node + 1];                                             \
        begA[gr] = b0;                                                         \
        int m_ = b1 - b0;                                                      \
        mA[gr] = m_;                                                           \
        idxA[gr][0] = (l15      < m_) ? (int)csr[b0 + l15     ] : N_NODES;     \
        idxA[gr][1] = (l15 + 16 < m_) ? (int)csr[b0 + l15 + 16] : N_NODES;     \
        idxA[gr][2] = (l15 + 32 < m_) ? (int)csr[b0 + l15 + 32] : N_NODES;     \
        idxA[gr][3] = (l15 + 48 < m_) ? (int)csr[b0 + l15 + 48] : N_NODES;     \
        unsigned eo = (unsigned)node * 16u + fg4;                              \
        eoffA[gr] = eo;                                                        \
        selfA[gr] = tbl_w[eo];                                                 \
        resA[gr] = __builtin_nontemporal_load(&h16_w[eo]);                     \
        ivA[gr] = inv[node];                                                   \
    }

    LOADG(0); LOADG(1); LOADG(2); LOADG(3);
#undef LOADG

#pragma unroll
    for (int gr = 0; gr < 4; gr++) {
        int mm = mA[gr];
        mm = max(mm, __shfl_xor(mm, 16));
        mm = max(mm, __shfl_xor(mm, 32));
        mmA[gr] = mm;
    }

#define AGGR_CHUNK(IDX)                                                     \
    {                                                                       \
        _Pragma("unroll")                                                   \
        for (int jj = 0; jj < 16; jj += 4) {                                \
            int s = __shfl((IDX), (lane & 48) | (jj + g));                  \
            uint4 u = tbl[s * 4 + f];                                       \
            const __half2* p = (const __half2*)&u;                          \
            a0 = __hadd2(a0, p[0]);                                         \
            a1 = __hadd2(a1, p[1]);                                         \
            a2 = __hadd2(a2, p[2]);                                         \
            a3 = __hadd2(a3, p[3]);                                         \
        }                                                                   \
    }

#define COMPG(gr)                                                              \
    {                                                                          \
        __half2 a0 = __floats2half2_rn(0.f, 0.f), a1 = a0, a2 = a0, a3 = a0;   \
        int mm = mmA[gr];                                                      \
        AGGR_CHUNK(idxA[gr][0]);                                               \
        if (mm > 16) AGGR_CHUNK(idxA[gr][1]);                                  \
        if (mm > 32) AGGR_CHUNK(idxA[gr][2]);                                  \
        if (mm > 48) AGGR_CHUNK(idxA[gr][3]);                                  \
        for (int eo = 64; eo < mm; eo += 16) {    /* deg>64: ~never */         \
            int e = eo + l15;                                                  \
            int idx = (e < mA[gr]) ? (int)csr[begA[gr] + e] : N_NODES;         \
            AGGR_CHUNK(idx);                                                   \
        }                                                                      \
        __half2 accv[4] = {a0, a1, a2, a3};                                    \
        _Pragma("unroll")                                                      \
        for (int i = 0; i < 4; i++) {                                          \
            unsigned pk = *(unsigned*)&accv[i];                                \
            int q = __shfl_xor((int)pk, 4);                                    \
            accv[i] = __hadd2(accv[i], *(__half2*)&q);                         \
            pk = *(unsigned*)&accv[i];                                         \
            q = __shfl_xor((int)pk, 8);                                        \
            accv[i] = __hadd2(accv[i], *(__half2*)&q);                         \
        }                                                                      \
        unsigned A0 = *(unsigned*)&accv[0], A1 = *(unsigned*)&accv[1];         \
        unsigned A2 = *(unsigned*)&accv[2], A3 = *(unsigned*)&accv[3];         \
        unsigned v01 = (g & 1) ? A1 : A0;                                      \
        unsigned v23 = (g & 1) ? A3 : A2;                                      \
        unsigned Asel = (g & 2) ? v23 : v01;                                   \
        float2 acc2 = __half22float2(*(__half2*)&Asel);                        \
        float2 slf2 = __half22float2(*(__half2*)&selfA[gr]);                   \
        float2 res2 = __half22float2(*(__half2*)&resA[gr]);                    \
        float iv = ivA[gr];                                                    \
        float r0 = fmaxf(fmaf((acc2.x + slf2.x) * iv, scl.x, shf.x), 0.f) + res2.x; \
        float r1 = fmaxf(fmaf((acc2.y + slf2.y) * iv, scl.y, shf.y), 0.f) + res2.y; \
        __half2 qo = __floats2half2_rn(r0, r1);                                \
        if (nodeA[gr] < N_NODES)                                               \
            __builtin_nontemporal_store(*(unsigned*)&qo,                       \
                                        (unsigned*)&h16_w[eoffA[gr]]);         \
    }

    COMPG(0); COMPG(1); COMPG(2); COMPG(3);
#undef COMPG
#undef AGGR_CHUNK
}

// ---- pooling: one block per graph, fp16 in (slice-major) / fp16 out --------
__global__ void k_pool(const ushort* __restrict__ h16, const int* __restrict__ batch,
                       ushort* __restrict__ gp16) {
    int g = blockIdx.x;
    __shared__ int s_lo, s_hi;
    if (threadIdx.x == 0) {
        int lo = 0, hi = N_NODES;
        while (lo < hi) { int m = (lo + hi) >> 1; if (batch[m] < g) lo = m + 1; else hi = m; }
        s_lo = lo;
        hi = N_NODES;
        while (lo < hi) { int m = (lo + hi) >> 1; if (batch[m] < g + 1) lo = m + 1; else hi = m; }
        s_hi = lo;
    }
    __syncthreads();
    int lo = s_lo, hi = s_hi;
    int t = threadIdx.x;
    const ushort* col = h16 + ((size_t)(t >> 5) * NPAD) * 32 + (t & 31);
    float sum = 0.0f, mx = -1e30f;
    for (int n = lo; n < hi; n++) {
        float v = __half2float(__ushort_as_half(col[(size_t)n * 32]));
        sum += v;
        mx = fmaxf(mx, v);
    }
    float cntf = fmaxf((float)(hi - lo), 1.0f);
    float mean = sum / cntf;
    float mxo = (hi > lo) ? mx : 0.0f;
    gp16[(size_t)g * 2 * HDIM + t] = __half_as_ushort(__float2half(mean));
    gp16[(size_t)g * 2 * HDIM + HDIM + t] = __half_as_ushort(__float2half(mxo));
}

// ---- head1 via MFMA: g1h = fp16(relu(gp16 @ W1 + b1)) ----------------------
__global__ __launch_bounds__(256) void k_head1_mfma(const ushort* __restrict__ A,
                                                    const _Float16* __restrict__ Bt,
                                                    const float* __restrict__ bias,
                                                    ushort* __restrict__ out16) {
    constexpr int K = 512, LDKH = 520;
    __shared__ _Float16 hs[64 * LDKH];
    int block_r = blockIdx.x * 64;
    for (int i = threadIdx.x; i < 64 * (K / 8); i += 256) {
        int row = i / (K / 8);
        int c = (i % (K / 8)) * 8;
        *(uint4*)&hs[row * LDKH + c] = *(const uint4*)(A + (size_t)(block_r + row) * K + c);
    }
    __syncthreads();

    int wave = threadIdx.x >> 6;
    int lane = threadIdx.x & 63;
    int l16 = lane & 15;
    int quad = lane >> 4;
    int n0 = wave * 64;

    f32x4 acc[4][4] = {};
    for (int k0 = 0; k0 < K; k0 += 32) {
        half8 a[4], b[4];
#pragma unroll
        for (int ai = 0; ai < 4; ai++)
            a[ai] = *(const half8*)&hs[(ai * 16 + l16) * LDKH + k0 + quad * 8];
#pragma unroll
        for (int bj = 0; bj < 4; bj++)
            b[bj] = *(const half8*)&Bt[(size_t)(n0 + bj * 16 + l16) * K + k0 + quad * 8];
#pragma unroll
        for (int ai = 0; ai < 4; ai++)
#pragma unroll
            for (int bj = 0; bj < 4; bj++)
                acc[ai][bj] = __builtin_amdgcn_mfma_f32_16x16x32_f16(a[ai], b[bj], acc[ai][bj], 0, 0, 0);
    }

#pragma unroll
    for (int ai = 0; ai < 4; ai++) {
        int rowb = block_r + ai * 16 + quad * 4;
#pragma unroll
        for (int r = 0; r < 4; r++) {
            int row = rowb + r;
#pragma unroll
            for (int bj = 0; bj < 4; bj++) {
                int col = n0 + bj * 16 + l16;
                float v = fmaxf(acc[ai][bj][r] + bias[col], 0.f);
                out16[(size_t)row * HDIM + col] = __half_as_ushort(__float2half(v));
            }
        }
    }
}

// ---- fused head2 + head3: block = 64 graphs, 128 threads -------------------
__global__ __launch_bounds__(128) void k_head23(const ushort* __restrict__ g1h,
                                                const _Float16* __restrict__ W2t,
                                                const float* __restrict__ b2,
                                                const float* __restrict__ W3,
                                                const float* __restrict__ b3,
                                                float* __restrict__ out) {
    __shared__ _Float16 hs[64 * 264];
    __shared__ float g2s[64 * 132];
    int block_r = blockIdx.x * 64;
    for (int i = threadIdx.x; i < 64 * 32; i += 128) {
        int row = i >> 5;
        int c = (i & 31) * 8;
        *(uint4*)&hs[row * 264 + c] = *(const uint4*)(g1h + (size_t)(block_r + row) * HDIM + c);
    }
    __syncthreads();

    int wave = threadIdx.x >> 6;
    int lane = threadIdx.x & 63;
    int l16 = lane & 15;
    int quad = lane >> 4;
    int n0 = wave * 64;

    f32x4 acc[4][4] = {};
    for (int k0 = 0; k0 < HDIM; k0 += 32) {
        half8 a[4], b[4];
#pragma unroll
        for (int ai = 0; ai < 4; ai++)
            a[ai] = *(const half8*)&hs[(ai * 16 + l16) * 264 + k0 + quad * 8];
#pragma unroll
        for (int bj = 0; bj < 4; bj++)
            b[bj] = *(const half8*)&W2t[(size_t)(n0 + bj * 16 + l16) * HDIM + k0 + quad * 8];
#pragma unroll
        for (int ai = 0; ai < 4; ai++)
#pragma unroll
            for (int bj = 0; bj < 4; bj++)
                acc[ai][bj] = __builtin_amdgcn_mfma_f32_16x16x32_f16(a[ai], b[bj], acc[ai][bj], 0, 0, 0);
    }
#pragma unroll
    for (int ai = 0; ai < 4; ai++) {
        int rowb = ai * 16 + quad * 4;
#pragma unroll
        for (int r = 0; r < 4; r++) {
            int row = rowb + r;
#pragma unroll
            for (int bj = 0; bj < 4; bj++) {
                int col = n0 + bj * 16 + l16;
                g2s[row * 132 + col] = fmaxf(acc[ai][bj][r] + b2[col], 0.f);
            }
        }
    }
    __syncthreads();

    // head3: 64 rows x 4 cols; thread -> (row, col pair)
    int r = threadIdx.x >> 1;
    int p = threadIdx.x & 1;
    float a0 = b3[2 * p], a1 = b3[2 * p + 1];
    for (int k = 0; k < 128; k++) {
        float v = g2s[r * 132 + k];
        a0 += v * W3[k * T_OUT + 2 * p];
        a1 += v * W3[k * T_OUT + 2 * p + 1];
    }
    out[(size_t)(block_r + r) * T_OUT + 2 * p] = a0;
    out[(size_t)(block_r + r) * T_OUT + 2 * p + 1] = a1;
}

extern "C" void kernel_launch(void* const* d_in, const int* in_sizes, int n_in,
                              void* d_out, int out_size, void* d_ws, size_t ws_size,
                              hipStream_t stream) {
    const float* x     = (const float*)d_in[0];
    const int*   ei    = (const int*)d_in[1];
    const int*   batch = (const int*)d_in[2];
    const float* projW = (const float*)d_in[3];
    const float* projb = (const float*)d_in[4];
    const float* convW = (const float*)d_in[5];
    const float* convb = (const float*)d_in[6];
    const float* gamma = (const float*)d_in[7];
    const float* beta  = (const float*)d_in[8];
    const float* mean  = (const float*)d_in[9];
    const float* var   = (const float*)d_in[10];
    const float* W1    = (const float*)d_in[11];
    const float* b1    = (const float*)d_in[12];
    const float* W2    = (const float*)d_in[13];
    const float* b2    = (const float*)d_in[14];
    const float* W3    = (const float*)d_in[15];
    const float* b3    = (const float*)d_in[16];
    float* out = (float*)d_out;

    // workspace layout (all segments 16B aligned)
    float*  wsf    = (float*)d_ws;
    float*  inv    = wsf;                        // NPAD f
    int*    cnt    = (int*)(wsf + NPAD);         // NPAD i
    int*    rowptr = cnt + NPAD;                 // NPAD i
    int*    wpos   = rowptr + NPAD;              // NPAD i
    int*    iscan  = wpos + NPAD;                // NPAD i
    int*    bsum   = iscan + NPAD;               // 256 i
    int*    boff   = bsum + 256;                 // 256 i (unused, kept for layout)
    ushort* csr    = (ushort*)(boff + 256);      // 800256 u16
    ushort* hWh    = csr + 800256;               // [8][NPAD][32] fp16 messages (slice-major)
    ushort* h16    = hWh + (size_t)NPAD * 256;   // [8][NPAD][32] fp16 residual (slice-major)
    ushort* gp16   = h16 + (size_t)NPAD * 256;   // G*512 fp16
    ushort* g1h    = gp16 + (size_t)G_GRAPHS * 512;           // G*256 fp16
    _Float16* Wt   = (_Float16*)(g1h + (size_t)G_GRAPHS * HDIM); // WT_TOT fp16
    float*  bnp    = (float*)(Wt + WT_TOT);                   // 2*L*H f (scale | shift)

    // ---- CSR build + weight transposes + BN precompute + zero rows ----
    hipMemsetAsync(cnt, 0, NPAD * sizeof(int), stream);
    k_deg_wcvt<<<(E_EDGES + 255) / 256, 256, 0, stream>>>(ei + E_EDGES, cnt,
                                                          convW, projW, W1, W2, Wt,
                                                          convb, gamma, beta, mean, var, bnp,
                                                          hWh);
    k_scan1<<<NBLK, 256, 0, stream>>>(cnt, iscan, bsum);
    k_scan23<<<NBLK, 256, 0, stream>>>(cnt, iscan, bsum, rowptr, wpos, inv);
    k_scatter<<<(E_EDGES + 255) / 256, 256, 0, stream>>>(ei, wpos, csr);

    // ---- proj (MFMA) ----
    int gemm_blocks = (N_NODES + 63) / 64;
    k_proj_mfma<<<gemm_blocks, 256, 0, stream>>>(x, Wt + WT_PROJ, projb, h16, N_NODES);

    // ---- GCN layers ----
    for (int l = 0; l < L_LAYERS; l++) {
        k_gemm_mfma<<<gemm_blocks, 256, 0, stream>>>(h16, Wt + WT_CONV + (size_t)l * HDIM * HDIM,
                                                     inv, (_Float16*)hWh, N_NODES);
        k_aggr<<<AGG_BLK * SLICES, 256, 0, stream>>>(rowptr, csr, hWh, inv,
                                                     bnp + l * HDIM,
                                                     bnp + L_LAYERS * HDIM + l * HDIM, h16);
    }

    // ---- pool + head ----
    k_pool<<<G_GRAPHS, HDIM, 0, stream>>>(h16, batch, gp16);
    k_head1_mfma<<<G_GRAPHS / 64, 256, 0, stream>>>(gp16, Wt + WT_H1, b1, g1h);
    k_head23<<<G_GRAPHS / 64, 128, 0, stream>>>(g1h, Wt + WT_H2, b2, W3, b3, out);
}

// Round 7
// 551.304 us; speedup vs baseline: 1.0574x; 1.0574x over previous
//
#include <hip/hip_runtime.h>
#include <hip/hip_bf16.h>
#include <hip/hip_fp16.h>

#define N_NODES 50000
#define F_IN    64
#define HDIM    256
#define E_EDGES 800000
#define G_GRAPHS 2048
#define L_LAYERS 4
#define T_OUT   4
#define BN_EPS  1e-5f

#define NPAD    50176   // 196 * 256
#define NBLK    196
#define LDK     264     // fp16 LDS row stride for K=256 tiles
#define SLICES  8       // feature slices (one per XCD); 32 fp16 = 64B each

// Wt buffer offsets (fp16 elements)
#define WT_CONV 0
#define WT_PROJ 262144
#define WT_H1   278528
#define WT_H2   409600
#define WT_TOT  442368

typedef _Float16 half8 __attribute__((ext_vector_type(8)));
typedef float    f32x4 __attribute__((ext_vector_type(4)));
typedef unsigned int u32x4 __attribute__((ext_vector_type(4)));

// ---- degree count + weight transposes + BN precompute + zero rows ----------
__global__ void k_deg_wcvt(const int* __restrict__ dst, int* __restrict__ cnt,
                           const float* __restrict__ convW, const float* __restrict__ projW,
                           const float* __restrict__ W1, const float* __restrict__ W2,
                           _Float16* __restrict__ Wt,
                           const float* __restrict__ convb, const float* __restrict__ gamma,
                           const float* __restrict__ beta, const float* __restrict__ mean,
                           const float* __restrict__ var, float* __restrict__ bnp,
                           ushort* __restrict__ Wh) {
    int i = blockIdx.x * 256 + threadIdx.x;
    if (i < E_EDGES) atomicAdd(&cnt[dst[i]], 1);
    if (i < 262144) {                       // conv: 4 x [256x256]
        int l = i >> 16, r = i & 65535;
        int k = r >> 8, n = r & 255;
        Wt[WT_CONV + (size_t)l * 65536 + n * 256 + k] = (_Float16)convW[(size_t)l * 65536 + k * 256 + n];
        return;
    }
    int j = i - 262144;
    if (j >= 0 && j < 16384) {              // proj: [64x256] -> [256][64]
        int k = j >> 8, n = j & 255;
        Wt[WT_PROJ + n * 64 + k] = (_Float16)projW[k * 256 + n];
        return;
    }
    j -= 16384;
    if (j >= 0 && j < 131072) {             // W1: [512x256] -> [256][512]
        int k = j >> 8, n = j & 255;
        Wt[WT_H1 + n * 512 + k] = (_Float16)W1[k * 256 + n];
        return;
    }
    j -= 131072;
    if (j >= 0 && j < 32768) {              // W2: [256x128] -> [128][256]
        int k = j >> 7, n = j & 127;
        Wt[WT_H2 + n * 256 + k] = (_Float16)W2[k * 128 + n];
        return;
    }
    j -= 32768;
    if (j >= 0 && j < L_LAYERS * HDIM) {    // BN: scale = g*rsqrt(v+eps), shift = (cb-m)*scale+b
        float scv = gamma[j] * rsqrtf(var[j] + BN_EPS);
        bnp[j] = scv;
        bnp[L_LAYERS * HDIM + j] = (convb[j] - mean[j]) * scv + beta[j];
        return;
    }
    j -= L_LAYERS * HDIM;
    if (j >= 0 && j < SLICES * 32) {        // zero row (idx N_NODES) in each slice of hWh
        int sl = j >> 5, w = j & 31;
        Wh[((size_t)sl * NPAD + N_NODES) * 32 + w] = 0;
    }
}

// ---- scan pass 1: per-block inclusive scan ---------------------------------
__global__ void k_scan1(const int* __restrict__ cnt, int* __restrict__ iscan,
                        int* __restrict__ bsum) {
    __shared__ int sm[256];
    int t = threadIdx.x, i = blockIdx.x * 256 + t;
    sm[t] = cnt[i];
    __syncthreads();
    for (int off = 1; off < 256; off <<= 1) {
        int u = (t >= off) ? sm[t - off] : 0;
        __syncthreads();
        sm[t] += u;
        __syncthreads();
    }
    iscan[i] = sm[t];
    if (t == 255) bsum[blockIdx.x] = sm[255];
}

// ---- scan pass 2: block offset computed locally + emit rowptr/wpos/inv -----
__global__ void k_scan23(const int* __restrict__ cnt, const int* __restrict__ iscan,
                         const int* __restrict__ bsum, int* __restrict__ rowptr,
                         int* __restrict__ wpos, float* __restrict__ inv) {
    __shared__ int sm[256];
    int t = threadIdx.x;
    int b = blockIdx.x;
    sm[t] = (t < b) ? bsum[t] : 0;   // t < b <= 195 < NBLK
    __syncthreads();
    for (int off = 128; off > 0; off >>= 1) {
        if (t < off) sm[t] += sm[t + off];
        __syncthreads();
    }
    int boff = sm[0];
    int i = b * 256 + t;
    int c = cnt[i];
    int excl = boff + iscan[i] - c;
    rowptr[i] = excl;
    wpos[i] = excl;
    inv[i] = rsqrtf((float)c + 1.0f);
}

// ---- scatter edges into CSR order (src ids fit in ushort: N < 65536) -------
__global__ void k_scatter(const int* __restrict__ ei, int* __restrict__ wpos,
                          ushort* __restrict__ csr_src) {
    int e = blockIdx.x * blockDim.x + threadIdx.x;
    if (e < E_EDGES) {
        int s = ei[e];
        int d = ei[E_EDGES + e];
        int pos = atomicAdd(&wpos[d], 1);
        csr_src[pos] = (ushort)s;
    }
}

// ---- proj GEMM via MFMA: h16 = fp16(relu(x @ Wp + b)), slice-major out -----
// Epilogue stages the 64x256 fp16 tile in LDS, then stores 1KB-contiguous
// (16 rows x 64B per instr) instead of 2B scattered stores.
__global__ __launch_bounds__(256) void k_proj_mfma(const float* __restrict__ x,
                                                   const _Float16* __restrict__ Wpt,
                                                   const float* __restrict__ bias,
                                                   ushort* __restrict__ h16, int nrows) {
    __shared__ _Float16 hs[64 * 264];     // A staged at stride 72; output tile at stride 264
    int block_r = blockIdx.x * 64;
    for (int i = threadIdx.x; i < 64 * 16; i += 256) {
        int row = i >> 4;
        int c4 = (i & 15) * 4;
        float4 v = (block_r + row < nrows)
                       ? *(const float4*)(x + (size_t)(block_r + row) * F_IN + c4)
                       : make_float4(0.f, 0.f, 0.f, 0.f);
        _Float16* p = &hs[row * 72 + c4];
        p[0] = (_Float16)v.x; p[1] = (_Float16)v.y;
        p[2] = (_Float16)v.z; p[3] = (_Float16)v.w;
    }
    __syncthreads();

    int wave = threadIdx.x >> 6;
    int lane = threadIdx.x & 63;
    int l16 = lane & 15;
    int quad = lane >> 4;
    int n0 = wave * 64;

    f32x4 acc[4][4] = {};
#pragma unroll
    for (int k0 = 0; k0 < F_IN; k0 += 32) {
        half8 a[4], b[4];
#pragma unroll
        for (int ai = 0; ai < 4; ai++)
            a[ai] = *(const half8*)&hs[(ai * 16 + l16) * 72 + k0 + quad * 8];
#pragma unroll
        for (int bj = 0; bj < 4; bj++)
            b[bj] = *(const half8*)&Wpt[(size_t)(n0 + bj * 16 + l16) * F_IN + k0 + quad * 8];
#pragma unroll
        for (int ai = 0; ai < 4; ai++)
#pragma unroll
            for (int bj = 0; bj < 4; bj++)
                acc[ai][bj] = __builtin_amdgcn_mfma_f32_16x16x32_f16(a[ai], b[bj], acc[ai][bj], 0, 0, 0);
    }
    __syncthreads();          // all waves done reading A before overwrite

#pragma unroll
    for (int ai = 0; ai < 4; ai++) {
#pragma unroll
        for (int r = 0; r < 4; r++) {
            int lrow = ai * 16 + quad * 4 + r;
#pragma unroll
            for (int bj = 0; bj < 4; bj++) {
                int col = n0 + bj * 16 + l16;
                float v = fmaxf(acc[ai][bj][r] + bias[col], 0.f);
                hs[lrow * 264 + col] = (_Float16)v;
            }
        }
    }
    __syncthreads();

    for (int i = threadIdx.x; i < 2048; i += 256) {   // 8 slices x 64 rows x 4 granules
        int s = i >> 8;
        int j = i & 255;
        int lrow = j >> 2;
        int q = j & 3;
        if (block_r + lrow < nrows)
            *(uint4*)(h16 + ((size_t)s * NPAD + block_r + lrow) * 32 + q * 8) =
                *(const uint4*)&hs[lrow * 264 + s * 32 + q * 8];
    }
}

// ---- conv GEMM via MFMA: hWh = fp16((h16 @ W) * inv[row]), slice-major -----
// Same LDS-staged coalesced epilogue.
__global__ __launch_bounds__(256) void k_gemm_mfma(const ushort* __restrict__ h16,
                                                   const _Float16* __restrict__ Wt,
                                                   const float* __restrict__ inv,
                                                   _Float16* __restrict__ outh, int nrows) {
    __shared__ _Float16 hs[64 * LDK];
    int block_r = blockIdx.x * 64;
    for (int i = threadIdx.x; i < 64 * 32; i += 256) {
        int row = i >> 5;
        int q = i & 31;             // slice = q>>2, 16B granule = q&3
        uint4 v;
        if (block_r + row < nrows)
            v = *(const uint4*)(h16 + ((size_t)(q >> 2) * NPAD + block_r + row) * 32 + (q & 3) * 8);
        else
            v = make_uint4(0u, 0u, 0u, 0u);
        *(uint4*)&hs[row * LDK + q * 8] = v;
    }
    __syncthreads();

    int wave = threadIdx.x >> 6;
    int lane = threadIdx.x & 63;
    int l16 = lane & 15;
    int quad = lane >> 4;
    int n0 = wave * 64;

    f32x4 acc[4][4] = {};
    for (int k0 = 0; k0 < HDIM; k0 += 32) {
        half8 a[4], b[4];
#pragma unroll
        for (int ai = 0; ai < 4; ai++)
            a[ai] = *(const half8*)&hs[(ai * 16 + l16) * LDK + k0 + quad * 8];
#pragma unroll
        for (int bj = 0; bj < 4; bj++)
            b[bj] = *(const half8*)&Wt[(size_t)(n0 + bj * 16 + l16) * HDIM + k0 + quad * 8];
#pragma unroll
        for (int ai = 0; ai < 4; ai++)
#pragma unroll
            for (int bj = 0; bj < 4; bj++)
                acc[ai][bj] = __builtin_amdgcn_mfma_f32_16x16x32_f16(a[ai], b[bj], acc[ai][bj], 0, 0, 0);
    }
    __syncthreads();

#pragma unroll
    for (int ai = 0; ai < 4; ai++) {
#pragma unroll
        for (int r = 0; r < 4; r++) {
            int lrow = ai * 16 + quad * 4 + r;
            float sc = inv[block_r + lrow];      // inv is NPAD-sized: phantom rows safe
#pragma unroll
            for (int bj = 0; bj < 4; bj++) {
                int col = n0 + bj * 16 + l16;
                hs[lrow * LDK + col] = (_Float16)(acc[ai][bj][r] * sc);
            }
        }
    }
    __syncthreads();

    for (int i = threadIdx.x; i < 2048; i += 256) {
        int s = i >> 8;
        int j = i & 255;
        int lrow = j >> 2;
        int q = j & 3;
        if (block_r + lrow < nrows)
            *(uint4*)((ushort*)outh + ((size_t)s * NPAD + block_r + lrow) * 32 + q * 8) =
                *(const uint4*)&hs[lrow * LDK + s * 32 + q * 8];
    }
}

// ---- fused CSR aggregation, feature-sliced across XCDs (round-5 proven) ----
__global__ __launch_bounds__(256) void k_aggr(const int* __restrict__ rowptr,
                                              const ushort* __restrict__ csr,
                                              const ushort* __restrict__ hWh,
                                              const float* __restrict__ inv,
                                              const float* __restrict__ bnscale,
                                              const float* __restrict__ bnshift,
                                              ushort* __restrict__ h16) {
    int slice = blockIdx.x & 7;
    int chunk = blockIdx.x >> 3;
    int lane = threadIdx.x & 63;
    int wv = threadIdx.x >> 6;
    int nb = lane >> 4;            // node sub 0..3
    int g  = (lane >> 2) & 3;      // edge slot / half2-pair 0..3
    int f  = lane & 3;             // 16B granule 0..3
    int node = chunk * 16 + wv * 4 + nb;   // grid covers exactly N_NODES

    const uint4* tbl = (const uint4*)hWh + (size_t)slice * (NPAD * 4);
    const unsigned* tbl_w = (const unsigned*)tbl;
    const unsigned* h16_w = (const unsigned*)h16 + (size_t)slice * (NPAD * 16);

    int beg = rowptr[node], end = rowptr[node + 1];
    int m = end - beg;
    int l15 = lane & 15;

    // preload up to 64 edge indices per node (cached; csr reused across layers)
    int idx0 = (l15      < m) ? (int)csr[beg + l15     ] : N_NODES;
    int idx1 = (l15 + 16 < m) ? (int)csr[beg + l15 + 16] : N_NODES;
    int idx2 = (l15 + 32 < m) ? (int)csr[beg + l15 + 32] : N_NODES;
    int idx3 = (l15 + 48 < m) ? (int)csr[beg + l15 + 48] : N_NODES;

    // per-lane 4B self (hot table) + residual (single-use -> NT), issued early
    unsigned eoff = (unsigned)node * 16u + (unsigned)(f * 4 + g);   // dword idx
    unsigned self_u = tbl_w[eoff];
    unsigned res_u  = __builtin_nontemporal_load(&h16_w[eoff]);
    float iv = inv[node];

    // wave-uniform chunk count (pad -> zero row)
    int mm = m;
    mm = max(mm, __shfl_xor(mm, 16));
    mm = max(mm, __shfl_xor(mm, 32));

    __half2 a0 = __floats2half2_rn(0.f, 0.f), a1 = a0, a2 = a0, a3 = a0;

#define AGGR_CHUNK(IDX)                                                     \
    {                                                                       \
        _Pragma("unroll")                                                   \
        for (int jj = 0; jj < 16; jj += 4) {                                \
            int s = __shfl((IDX), (lane & 48) | (jj + g));                  \
            uint4 u = tbl[s * 4 + f];                                       \
            const __half2* p = (const __half2*)&u;                          \
            a0 = __hadd2(a0, p[0]);                                         \
            a1 = __hadd2(a1, p[1]);                                         \
            a2 = __hadd2(a2, p[2]);                                         \
            a3 = __hadd2(a3, p[3]);                                         \
        }                                                                   \
    }

    AGGR_CHUNK(idx0);
    if (mm > 16) AGGR_CHUNK(idx1);
    if (mm > 32) AGGR_CHUNK(idx2);
    if (mm > 48) AGGR_CHUNK(idx3);
    // safety tail for degree > 64 (essentially never for Poisson(16))
    for (int eo = 64; eo < mm; eo += 16) {
        int e = eo + l15;
        int idx = (e < m) ? (int)csr[beg + e] : N_NODES;
        AGGR_CHUNK(idx);
    }
#undef AGGR_CHUNK

    // reduce across the 4 edge slots (lane bits 2,3); full sum in all lanes
    __half2 accv[4] = {a0, a1, a2, a3};
#pragma unroll
    for (int i = 0; i < 4; i++) {
        unsigned pk = *(unsigned*)&accv[i];
        int q = __shfl_xor((int)pk, 4);
        accv[i] = __hadd2(accv[i], *(__half2*)&q);
        pk = *(unsigned*)&accv[i];
        q = __shfl_xor((int)pk, 8);
        accv[i] = __hadd2(accv[i], *(__half2*)&q);
    }

    // lane (g,f) finishes half2-pair g of granule f (3 cndmask selects)
    unsigned A0 = *(unsigned*)&accv[0], A1 = *(unsigned*)&accv[1];
    unsigned A2 = *(unsigned*)&accv[2], A3 = *(unsigned*)&accv[3];
    unsigned v01 = (g & 1) ? A1 : A0;
    unsigned v23 = (g & 1) ? A3 : A2;
    unsigned Asel = (g & 2) ? v23 : v01;

    float2 acc2 = __half22float2(*(__half2*)&Asel);
    float2 slf2 = __half22float2(*(__half2*)&self_u);
    float2 res2 = __half22float2(*(__half2*)&res_u);
    int c0f = slice * 32 + f * 8 + g * 2;
    float2 scl = *(const float2*)(bnscale + c0f);
    float2 shf = *(const float2*)(bnshift + c0f);
    float r0 = fmaxf(fmaf((acc2.x + slf2.x) * iv, scl.x, shf.x), 0.f) + res2.x;
    float r1 = fmaxf(fmaf((acc2.y + slf2.y) * iv, scl.y, shf.y), 0.f) + res2.y;
    __half2 qo = __floats2half2_rn(r0, r1);
    __builtin_nontemporal_store(*(unsigned*)&qo, (unsigned*)&h16_w[eoff]);
}

// ---- pooling: one block per graph, vectorized 16B loads + 2-level reduce ---
__global__ __launch_bounds__(256) void k_pool(const ushort* __restrict__ h16,
                                              const int* __restrict__ batch,
                                              ushort* __restrict__ gp16) {
    int g = blockIdx.x;
    __shared__ int s_lo, s_hi;
    __shared__ float sm_sum[4][256];
    __shared__ float sm_max[4][256];
    if (threadIdx.x == 0) {
        int lo = 0, hi = N_NODES;
        while (lo < hi) { int m = (lo + hi) >> 1; if (batch[m] < g) lo = m + 1; else hi = m; }
        s_lo = lo;
        hi = N_NODES;
        while (lo < hi) { int m = (lo + hi) >> 1; if (batch[m] < g + 1) lo = m + 1; else hi = m; }
        s_hi = lo;
    }
    __syncthreads();
    int lo = s_lo, hi = s_hi;
    int t = threadIdx.x;
    int ng = t >> 5;              // node group 0..7
    int cg = t & 31;              // 8 cols starting cg*8
    const ushort* base = h16 + ((size_t)(cg >> 2) * NPAD) * 32 + (cg & 3) * 8;

    float s8[8], m8[8];
#pragma unroll
    for (int i = 0; i < 8; i++) { s8[i] = 0.f; m8[i] = -1e30f; }
    for (int n = lo + ng; n < hi; n += 8) {
        uint4 v = *(const uint4*)(base + (size_t)n * 32);
        const __half2* p = (const __half2*)&v;
#pragma unroll
        for (int i = 0; i < 4; i++) {
            float2 fv = __half22float2(p[i]);
            s8[2 * i]     += fv.x;
            s8[2 * i + 1] += fv.y;
            m8[2 * i]     = fmaxf(m8[2 * i], fv.x);
            m8[2 * i + 1] = fmaxf(m8[2 * i + 1], fv.y);
        }
    }
    // combine node-group pairs within the wave (lanes t, t^32)
#pragma unroll
    for (int i = 0; i < 8; i++) {
        s8[i] += __shfl_xor(s8[i], 32);
        m8[i] = fmaxf(m8[i], __shfl_xor(m8[i], 32));
    }
    int wv = t >> 6;
    if ((t & 32) == 0) {
#pragma unroll
        for (int i = 0; i < 8; i++) {
            sm_sum[wv][cg * 8 + i] = s8[i];
            sm_max[wv][cg * 8 + i] = m8[i];
        }
    }
    __syncthreads();
    float fs = sm_sum[0][t] + sm_sum[1][t] + sm_sum[2][t] + sm_sum[3][t];
    float fm = fmaxf(fmaxf(sm_max[0][t], sm_max[1][t]), fmaxf(sm_max[2][t], sm_max[3][t]));
    float cntf = fmaxf((float)(hi - lo), 1.0f);
    float mean = fs / cntf;
    float mxo = (hi > lo) ? fm : 0.0f;
    gp16[(size_t)g * 2 * HDIM + t] = __half_as_ushort(__float2half(mean));
    gp16[(size_t)g * 2 * HDIM + HDIM + t] = __half_as_ushort(__float2half(mxo));
}

// ---- head1 via MFMA: g1h = fp16(relu(gp16 @ W1 + b1)) ----------------------
__global__ __launch_bounds__(256) void k_head1_mfma(const ushort* __restrict__ A,
                                                    const _Float16* __restrict__ Bt,
                                                    const float* __restrict__ bias,
                                                    ushort* __restrict__ out16) {
    constexpr int K = 512, LDKH = 520;
    __shared__ _Float16 hs[64 * LDKH];
    int block_r = blockIdx.x * 64;
    for (int i = threadIdx.x; i < 64 * (K / 8); i += 256) {
        int row = i / (K / 8);
        int c = (i % (K / 8)) * 8;
        *(uint4*)&hs[row * LDKH + c] = *(const uint4*)(A + (size_t)(block_r + row) * K + c);
    }
    __syncthreads();

    int wave = threadIdx.x >> 6;
    int lane = threadIdx.x & 63;
    int l16 = lane & 15;
    int quad = lane >> 4;
    int n0 = wave * 64;

    f32x4 acc[4][4] = {};
    for (int k0 = 0; k0 < K; k0 += 32) {
        half8 a[4], b[4];
#pragma unroll
        for (int ai = 0; ai < 4; ai++)
            a[ai] = *(const half8*)&hs[(ai * 16 + l16) * LDKH + k0 + quad * 8];
#pragma unroll
        for (int bj = 0; bj < 4; bj++)
            b[bj] = *(const half8*)&Bt[(size_t)(n0 + bj * 16 + l16) * K + k0 + quad * 8];
#pragma unroll
        for (int ai = 0; ai < 4; ai++)
#pragma unroll
            for (int bj = 0; bj < 4; bj++)
                acc[ai][bj] = __builtin_amdgcn_mfma_f32_16x16x32_f16(a[ai], b[bj], acc[ai][bj], 0, 0, 0);
    }

#pragma unroll
    for (int ai = 0; ai < 4; ai++) {
        int rowb = block_r + ai * 16 + quad * 4;
#pragma unroll
        for (int r = 0; r < 4; r++) {
            int row = rowb + r;
#pragma unroll
            for (int bj = 0; bj < 4; bj++) {
                int col = n0 + bj * 16 + l16;
                float v = fmaxf(acc[ai][bj][r] + bias[col], 0.f);
                out16[(size_t)row * HDIM + col] = __half_as_ushort(__float2half(v));
            }
        }
    }
}

// ---- fused head2 + head3: block = 64 graphs, 128 threads -------------------
__global__ __launch_bounds__(128) void k_head23(const ushort* __restrict__ g1h,
                                                const _Float16* __restrict__ W2t,
                                                const float* __restrict__ b2,
                                                const float* __restrict__ W3,
                                                const float* __restrict__ b3,
                                                float* __restrict__ out) {
    __shared__ _Float16 hs[64 * 264];
    __shared__ float g2s[64 * 132];
    int block_r = blockIdx.x * 64;
    for (int i = threadIdx.x; i < 64 * 32; i += 128) {
        int row = i >> 5;
        int c = (i & 31) * 8;
        *(uint4*)&hs[row * 264 + c] = *(const uint4*)(g1h + (size_t)(block_r + row) * HDIM + c);
    }
    __syncthreads();

    int wave = threadIdx.x >> 6;
    int lane = threadIdx.x & 63;
    int l16 = lane & 15;
    int quad = lane >> 4;
    int n0 = wave * 64;

    f32x4 acc[4][4] = {};
    for (int k0 = 0; k0 < HDIM; k0 += 32) {
        half8 a[4], b[4];
#pragma unroll
        for (int ai = 0; ai < 4; ai++)
            a[ai] = *(const half8*)&hs[(ai * 16 + l16) * 264 + k0 + quad * 8];
#pragma unroll
        for (int bj = 0; bj < 4; bj++)
            b[bj] = *(const half8*)&W2t[(size_t)(n0 + bj * 16 + l16) * HDIM + k0 + quad * 8];
#pragma unroll
        for (int ai = 0; ai < 4; ai++)
#pragma unroll
            for (int bj = 0; bj < 4; bj++)
                acc[ai][bj] = __builtin_amdgcn_mfma_f32_16x16x32_f16(a[ai], b[bj], acc[ai][bj], 0, 0, 0);
    }
#pragma unroll
    for (int ai = 0; ai < 4; ai++) {
        int rowb = ai * 16 + quad * 4;
#pragma unroll
        for (int r = 0; r < 4; r++) {
            int row = rowb + r;
#pragma unroll
            for (int bj = 0; bj < 4; bj++) {
                int col = n0 + bj * 16 + l16;
                g2s[row * 132 + col] = fmaxf(acc[ai][bj][r] + b2[col], 0.f);
            }
        }
    }
    __syncthreads();

    // head3: 64 rows x 4 cols; thread -> (row, col pair)
    int r = threadIdx.x >> 1;
    int p = threadIdx.x & 1;
    float a0 = b3[2 * p], a1 = b3[2 * p + 1];
    for (int k = 0; k < 128; k++) {
        float v = g2s[r * 132 + k];
        a0 += v * W3[k * T_OUT + 2 * p];
        a1 += v * W3[k * T_OUT + 2 * p + 1];
    }
    out[(size_t)(block_r + r) * T_OUT + 2 * p] = a0;
    out[(size_t)(block_r + r) * T_OUT + 2 * p + 1] = a1;
}

extern "C" void kernel_launch(void* const* d_in, const int* in_sizes, int n_in,
                              void* d_out, int out_size, void* d_ws, size_t ws_size,
                              hipStream_t stream) {
    const float* x     = (const float*)d_in[0];
    const int*   ei    = (const int*)d_in[1];
    const int*   batch = (const int*)d_in[2];
    const float* projW = (const float*)d_in[3];
    const float* projb = (const float*)d_in[4];
    const float* convW = (const float*)d_in[5];
    const float* convb = (const float*)d_in[6];
    const float* gamma = (const float*)d_in[7];
    const float* beta  = (const float*)d_in[8];
    const float* mean  = (const float*)d_in[9];
    const float* var   = (const float*)d_in[10];
    const float* W1    = (const float*)d_in[11];
    const float* b1    = (const float*)d_in[12];
    const float* W2    = (const float*)d_in[13];
    const float* b2    = (const float*)d_in[14];
    const float* W3    = (const float*)d_in[15];
    const float* b3    = (const float*)d_in[16];
    float* out = (float*)d_out;

    // workspace layout (all segments 16B aligned)
    float*  wsf    = (float*)d_ws;
    float*  inv    = wsf;                        // NPAD f
    int*    cnt    = (int*)(wsf + NPAD);         // NPAD i
    int*    rowptr = cnt + NPAD;                 // NPAD i
    int*    wpos   = rowptr + NPAD;              // NPAD i
    int*    iscan  = wpos + NPAD;                // NPAD i
    int*    bsum   = iscan + NPAD;               // 256 i
    int*    boff   = bsum + 256;                 // 256 i (unused, kept for layout)
    ushort* csr    = (ushort*)(boff + 256);      // 800256 u16
    ushort* hWh    = csr + 800256;               // [8][NPAD][32] fp16 messages (slice-major)
    ushort* h16    = hWh + (size_t)NPAD * 256;   // [8][NPAD][32] fp16 residual (slice-major)
    ushort* gp16   = h16 + (size_t)NPAD * 256;   // G*512 fp16
    ushort* g1h    = gp16 + (size_t)G_GRAPHS * 512;           // G*256 fp16
    _Float16* Wt   = (_Float16*)(g1h + (size_t)G_GRAPHS * HDIM); // WT_TOT fp16
    float*  bnp    = (float*)(Wt + WT_TOT);                   // 2*L*H f (scale | shift)

    // ---- CSR build + weight transposes + BN precompute + zero rows ----
    hipMemsetAsync(cnt, 0, NPAD * sizeof(int), stream);
    k_deg_wcvt<<<(E_EDGES + 255) / 256, 256, 0, stream>>>(ei + E_EDGES, cnt,
                                                          convW, projW, W1, W2, Wt,
                                                          convb, gamma, beta, mean, var, bnp,
                                                          hWh);
    k_scan1<<<NBLK, 256, 0, stream>>>(cnt, iscan, bsum);
    k_scan23<<<NBLK, 256, 0, stream>>>(cnt, iscan, bsum, rowptr, wpos, inv);
    k_scatter<<<(E_EDGES + 255) / 256, 256, 0, stream>>>(ei, wpos, csr);

    // ---- proj (MFMA) ----
    int gemm_blocks = (N_NODES + 63) / 64;
    k_proj_mfma<<<gemm_blocks, 256, 0, stream>>>(x, Wt + WT_PROJ, projb, h16, N_NODES);

    // ---- GCN layers ----
    for (int l = 0; l < L_LAYERS; l++) {
        k_gemm_mfma<<<gemm_blocks, 256, 0, stream>>>(h16, Wt + WT_CONV + (size_t)l * HDIM * HDIM,
                                                     inv, (_Float16*)hWh, N_NODES);
        k_aggr<<<(N_NODES / 16) * SLICES, 256, 0, stream>>>(rowptr, csr, hWh, inv,
                                                            bnp + l * HDIM,
                                                            bnp + L_LAYERS * HDIM + l * HDIM, h16);
    }

    // ---- pool + head ----
    k_pool<<<G_GRAPHS, HDIM, 0, stream>>>(h16, batch, gp16);
    k_head1_mfma<<<G_GRAPHS / 64, 256, 0, stream>>>(gp16, Wt + WT_H1, b1, g1h);
    k_head23<<<G_GRAPHS / 64, 128, 0, stream>>>(g1h, Wt + WT_H2, b2, W3, b3, out);
}

// Round 8
// 529.263 us; speedup vs baseline: 1.1015x; 1.0416x over previous
//
#include <hip/hip_runtime.h>
#include <hip/hip_bf16.h>
#include <hip/hip_fp16.h>

#define N_NODES 50000
#define F_IN    64
#define HDIM    256
#define E_EDGES 800000
#define G_GRAPHS 2048
#define L_LAYERS 4
#define T_OUT   4
#define BN_EPS  1e-5f

#define NPAD    50176   // 196 * 256
#define NBLK    196
#define LDK     264     // fp16 LDS row stride for K=256 tiles
#define SLICES  8       // feature slices (one per XCD); 32 fp16 = 64B each

// Wt buffer offsets (fp16 elements)
#define WT_CONV 0
#define WT_PROJ 262144
#define WT_H1   278528
#define WT_H2   409600
#define WT_TOT  442368

typedef _Float16 half8 __attribute__((ext_vector_type(8)));
typedef float    f32x4 __attribute__((ext_vector_type(4)));
typedef unsigned int u32x4 __attribute__((ext_vector_type(4)));

// ---- degree count + weight transposes + BN precompute + zero rows ----------
__global__ void k_deg_wcvt(const int* __restrict__ dst, int* __restrict__ cnt,
                           const float* __restrict__ convW, const float* __restrict__ projW,
                           const float* __restrict__ W1, const float* __restrict__ W2,
                           _Float16* __restrict__ Wt,
                           const float* __restrict__ convb, const float* __restrict__ gamma,
                           const float* __restrict__ beta, const float* __restrict__ mean,
                           const float* __restrict__ var, float* __restrict__ bnp,
                           ushort* __restrict__ Wh) {
    int i = blockIdx.x * 256 + threadIdx.x;
    if (i < E_EDGES) atomicAdd(&cnt[dst[i]], 1);
    if (i < 262144) {                       // conv: 4 x [256x256]
        int l = i >> 16, r = i & 65535;
        int k = r >> 8, n = r & 255;
        Wt[WT_CONV + (size_t)l * 65536 + n * 256 + k] = (_Float16)convW[(size_t)l * 65536 + k * 256 + n];
        return;
    }
    int j = i - 262144;
    if (j >= 0 && j < 16384) {              // proj: [64x256] -> [256][64]
        int k = j >> 8, n = j & 255;
        Wt[WT_PROJ + n * 64 + k] = (_Float16)projW[k * 256 + n];
        return;
    }
    j -= 16384;
    if (j >= 0 && j < 131072) {             // W1: [512x256] -> [256][512]
        int k = j >> 8, n = j & 255;
        Wt[WT_H1 + n * 512 + k] = (_Float16)W1[k * 256 + n];
        return;
    }
    j -= 131072;
    if (j >= 0 && j < 32768) {              // W2: [256x128] -> [128][256]
        int k = j >> 7, n = j & 127;
        Wt[WT_H2 + n * 256 + k] = (_Float16)W2[k * 128 + n];
        return;
    }
    j -= 32768;
    if (j >= 0 && j < L_LAYERS * HDIM) {    // BN: scale = g*rsqrt(v+eps), shift = (cb-m)*scale+b
        float scv = gamma[j] * rsqrtf(var[j] + BN_EPS);
        bnp[j] = scv;
        bnp[L_LAYERS * HDIM + j] = (convb[j] - mean[j]) * scv + beta[j];
        return;
    }
    j -= L_LAYERS * HDIM;
    if (j >= 0 && j < SLICES * 32) {        // zero row (idx N_NODES) in each slice of hWh
        int sl = j >> 5, w = j & 31;
        Wh[((size_t)sl * NPAD + N_NODES) * 32 + w] = 0;
    }
}

// ---- scan pass 1: per-block inclusive scan ---------------------------------
__global__ void k_scan1(const int* __restrict__ cnt, int* __restrict__ iscan,
                        int* __restrict__ bsum) {
    __shared__ int sm[256];
    int t = threadIdx.x, i = blockIdx.x * 256 + t;
    sm[t] = cnt[i];
    __syncthreads();
    for (int off = 1; off < 256; off <<= 1) {
        int u = (t >= off) ? sm[t - off] : 0;
        __syncthreads();
        sm[t] += u;
        __syncthreads();
    }
    iscan[i] = sm[t];
    if (t == 255) bsum[blockIdx.x] = sm[255];
}

// ---- scan pass 2: block offset computed locally + emit rowptr/wpos/inv -----
__global__ void k_scan23(const int* __restrict__ cnt, const int* __restrict__ iscan,
                         const int* __restrict__ bsum, int* __restrict__ rowptr,
                         int* __restrict__ wpos, float* __restrict__ inv) {
    __shared__ int sm[256];
    int t = threadIdx.x;
    int b = blockIdx.x;
    sm[t] = (t < b) ? bsum[t] : 0;   // t < b <= 195 < NBLK
    __syncthreads();
    for (int off = 128; off > 0; off >>= 1) {
        if (t < off) sm[t] += sm[t + off];
        __syncthreads();
    }
    int boff = sm[0];
    int i = b * 256 + t;
    int c = cnt[i];
    int excl = boff + iscan[i] - c;
    rowptr[i] = excl;
    wpos[i] = excl;
    inv[i] = rsqrtf((float)c + 1.0f);
}

// ---- scatter edges into CSR order (src ids fit in ushort: N < 65536) -------
__global__ void k_scatter(const int* __restrict__ ei, int* __restrict__ wpos,
                          ushort* __restrict__ csr_src) {
    int e = blockIdx.x * blockDim.x + threadIdx.x;
    if (e < E_EDGES) {
        int s = ei[e];
        int d = ei[E_EDGES + e];
        int pos = atomicAdd(&wpos[d], 1);
        csr_src[pos] = (ushort)s;
    }
}

// ---- proj GEMM via MFMA: h16 = fp16(relu(x @ Wp + b)), slice-major out -----
__global__ __launch_bounds__(256) void k_proj_mfma(const float* __restrict__ x,
                                                   const _Float16* __restrict__ Wpt,
                                                   const float* __restrict__ bias,
                                                   ushort* __restrict__ h16, int nrows) {
    __shared__ _Float16 hs[64 * 264];     // A staged at stride 72; output tile at stride 264
    int block_r = blockIdx.x * 64;
    for (int i = threadIdx.x; i < 64 * 16; i += 256) {
        int row = i >> 4;
        int c4 = (i & 15) * 4;
        float4 v = (block_r + row < nrows)
                       ? *(const float4*)(x + (size_t)(block_r + row) * F_IN + c4)
                       : make_float4(0.f, 0.f, 0.f, 0.f);
        _Float16* p = &hs[row * 72 + c4];
        p[0] = (_Float16)v.x; p[1] = (_Float16)v.y;
        p[2] = (_Float16)v.z; p[3] = (_Float16)v.w;
    }
    __syncthreads();

    int wave = threadIdx.x >> 6;
    int lane = threadIdx.x & 63;
    int l16 = lane & 15;
    int quad = lane >> 4;
    int n0 = wave * 64;

    f32x4 acc[4][4] = {};
#pragma unroll
    for (int k0 = 0; k0 < F_IN; k0 += 32) {
        half8 a[4], b[4];
#pragma unroll
        for (int ai = 0; ai < 4; ai++)
            a[ai] = *(const half8*)&hs[(ai * 16 + l16) * 72 + k0 + quad * 8];
#pragma unroll
        for (int bj = 0; bj < 4; bj++)
            b[bj] = *(const half8*)&Wpt[(size_t)(n0 + bj * 16 + l16) * F_IN + k0 + quad * 8];
#pragma unroll
        for (int ai = 0; ai < 4; ai++)
#pragma unroll
            for (int bj = 0; bj < 4; bj++)
                acc[ai][bj] = __builtin_amdgcn_mfma_f32_16x16x32_f16(a[ai], b[bj], acc[ai][bj], 0, 0, 0);
    }
    __syncthreads();          // all waves done reading A before overwrite

#pragma unroll
    for (int ai = 0; ai < 4; ai++) {
#pragma unroll
        for (int r = 0; r < 4; r++) {
            int lrow = ai * 16 + quad * 4 + r;
#pragma unroll
            for (int bj = 0; bj < 4; bj++) {
                int col = n0 + bj * 16 + l16;
                float v = fmaxf(acc[ai][bj][r] + bias[col], 0.f);
                hs[lrow * 264 + col] = (_Float16)v;
            }
        }
    }
    __syncthreads();

    for (int i = threadIdx.x; i < 2048; i += 256) {   // 8 slices x 64 rows x 4 granules
        int s = i >> 8;
        int j = i & 255;
        int lrow = j >> 2;
        int q = j & 3;
        if (block_r + lrow < nrows)
            *(uint4*)(h16 + ((size_t)s * NPAD + block_r + lrow) * 32 + q * 8) =
                *(const uint4*)&hs[lrow * 264 + s * 32 + q * 8];
    }
}

// ---- conv GEMM via MFMA: hWh = fp16((h16 @ W) * inv[row]), slice-major -----
// 128x256 tile, 8 waves (2 row-groups x 4 col-groups), LDS-staged coalesced
// epilogue. A staged once per 128 rows; 391 blocks, 2 blocks/CU co-resident.
__global__ __launch_bounds__(512) void k_gemm_mfma(const ushort* __restrict__ h16,
                                                   const _Float16* __restrict__ Wt,
                                                   const float* __restrict__ inv,
                                                   _Float16* __restrict__ outh, int nrows) {
    __shared__ _Float16 hs[128 * LDK];    // 67.6 KB
    int block_r = blockIdx.x * 128;
    for (int i = threadIdx.x; i < 128 * 32; i += 512) {
        int row = i >> 5;
        int q = i & 31;             // slice = q>>2, 16B granule = q&3
        uint4 v;
        if (block_r + row < nrows)
            v = *(const uint4*)(h16 + ((size_t)(q >> 2) * NPAD + block_r + row) * 32 + (q & 3) * 8);
        else
            v = make_uint4(0u, 0u, 0u, 0u);
        *(uint4*)&hs[row * LDK + q * 8] = v;
    }
    __syncthreads();

    int wave = threadIdx.x >> 6;    // 0..7
    int wr = wave >> 2;             // row group 0..1
    int wc = wave & 3;              // col group 0..3
    int lane = threadIdx.x & 63;
    int l16 = lane & 15;
    int quad = lane >> 4;
    int n0 = wc * 64;
    int r0 = wr * 64;

    f32x4 acc[4][4] = {};
    for (int k0 = 0; k0 < HDIM; k0 += 32) {
        half8 a[4], b[4];
#pragma unroll
        for (int ai = 0; ai < 4; ai++)
            a[ai] = *(const half8*)&hs[(r0 + ai * 16 + l16) * LDK + k0 + quad * 8];
#pragma unroll
        for (int bj = 0; bj < 4; bj++)
            b[bj] = *(const half8*)&Wt[(size_t)(n0 + bj * 16 + l16) * HDIM + k0 + quad * 8];
#pragma unroll
        for (int ai = 0; ai < 4; ai++)
#pragma unroll
            for (int bj = 0; bj < 4; bj++)
                acc[ai][bj] = __builtin_amdgcn_mfma_f32_16x16x32_f16(a[ai], b[bj], acc[ai][bj], 0, 0, 0);
    }
    __syncthreads();

#pragma unroll
    for (int ai = 0; ai < 4; ai++) {
#pragma unroll
        for (int r = 0; r < 4; r++) {
            int lrow = r0 + ai * 16 + quad * 4 + r;
            float sc = inv[block_r + lrow];      // inv is NPAD-sized: phantom rows safe
#pragma unroll
            for (int bj = 0; bj < 4; bj++) {
                int col = n0 + bj * 16 + l16;
                hs[lrow * LDK + col] = (_Float16)(acc[ai][bj][r] * sc);
            }
        }
    }
    __syncthreads();

    for (int i = threadIdx.x; i < 4096; i += 512) {   // 8 slices x 128 rows x 4 granules
        int s = i >> 9;
        int j = i & 511;
        int lrow = j >> 2;
        int q = j & 3;
        if (block_r + lrow < nrows)
            *(uint4*)((ushort*)outh + ((size_t)s * NPAD + block_r + lrow) * 32 + q * 8) =
                *(const uint4*)&hs[lrow * LDK + s * 32 + q * 8];
    }
}

// ---- fused CSR aggregation, feature-sliced across XCDs (round-5 proven) ----
__global__ __launch_bounds__(256) void k_aggr(const int* __restrict__ rowptr,
                                              const ushort* __restrict__ csr,
                                              const ushort* __restrict__ hWh,
                                              const float* __restrict__ inv,
                                              const float* __restrict__ bnscale,
                                              const float* __restrict__ bnshift,
                                              ushort* __restrict__ h16) {
    int slice = blockIdx.x & 7;
    int chunk = blockIdx.x >> 3;
    int lane = threadIdx.x & 63;
    int wv = threadIdx.x >> 6;
    int nb = lane >> 4;            // node sub 0..3
    int g  = (lane >> 2) & 3;      // edge slot / half2-pair 0..3
    int f  = lane & 3;             // 16B granule 0..3
    int node = chunk * 16 + wv * 4 + nb;   // grid covers exactly N_NODES

    const uint4* tbl = (const uint4*)hWh + (size_t)slice * (NPAD * 4);
    const unsigned* tbl_w = (const unsigned*)tbl;
    const unsigned* h16_w = (const unsigned*)h16 + (size_t)slice * (NPAD * 16);

    int beg = rowptr[node], end = rowptr[node + 1];
    int m = end - beg;
    int l15 = lane & 15;

    // preload up to 64 edge indices per node (cached; csr reused across layers)
    int idx0 = (l15      < m) ? (int)csr[beg + l15     ] : N_NODES;
    int idx1 = (l15 + 16 < m) ? (int)csr[beg + l15 + 16] : N_NODES;
    int idx2 = (l15 + 32 < m) ? (int)csr[beg + l15 + 32] : N_NODES;
    int idx3 = (l15 + 48 < m) ? (int)csr[beg + l15 + 48] : N_NODES;

    // per-lane 4B self (hot table) + residual (single-use -> NT), issued early
    unsigned eoff = (unsigned)node * 16u + (unsigned)(f * 4 + g);   // dword idx
    unsigned self_u = tbl_w[eoff];
    unsigned res_u  = __builtin_nontemporal_load(&h16_w[eoff]);
    float iv = inv[node];

    // wave-uniform chunk count (pad -> zero row)
    int mm = m;
    mm = max(mm, __shfl_xor(mm, 16));
    mm = max(mm, __shfl_xor(mm, 32));

    __half2 a0 = __floats2half2_rn(0.f, 0.f), a1 = a0, a2 = a0, a3 = a0;

#define AGGR_CHUNK(IDX)                                                     \
    {                                                                       \
        _Pragma("unroll")                                                   \
        for (int jj = 0; jj < 16; jj += 4) {                                \
            int s = __shfl((IDX), (lane & 48) | (jj + g));                  \
            uint4 u = tbl[s * 4 + f];                                       \
            const __half2* p = (const __half2*)&u;                          \
            a0 = __hadd2(a0, p[0]);                                         \
            a1 = __hadd2(a1, p[1]);                                         \
            a2 = __hadd2(a2, p[2]);                                         \
            a3 = __hadd2(a3, p[3]);                                         \
        }                                                                   \
    }

    AGGR_CHUNK(idx0);
    if (mm > 16) AGGR_CHUNK(idx1);
    if (mm > 32) AGGR_CHUNK(idx2);
    if (mm > 48) AGGR_CHUNK(idx3);
    // safety tail for degree > 64 (essentially never for Poisson(16))
    for (int eo = 64; eo < mm; eo += 16) {
        int e = eo + l15;
        int idx = (e < m) ? (int)csr[beg + e] : N_NODES;
        AGGR_CHUNK(idx);
    }
#undef AGGR_CHUNK

    // reduce across the 4 edge slots (lane bits 2,3); full sum in all lanes
    __half2 accv[4] = {a0, a1, a2, a3};
#pragma unroll
    for (int i = 0; i < 4; i++) {
        unsigned pk = *(unsigned*)&accv[i];
        int q = __shfl_xor((int)pk, 4);
        accv[i] = __hadd2(accv[i], *(__half2*)&q);
        pk = *(unsigned*)&accv[i];
        q = __shfl_xor((int)pk, 8);
        accv[i] = __hadd2(accv[i], *(__half2*)&q);
    }

    // lane (g,f) finishes half2-pair g of granule f (3 cndmask selects)
    unsigned A0 = *(unsigned*)&accv[0], A1 = *(unsigned*)&accv[1];
    unsigned A2 = *(unsigned*)&accv[2], A3 = *(unsigned*)&accv[3];
    unsigned v01 = (g & 1) ? A1 : A0;
    unsigned v23 = (g & 1) ? A3 : A2;
    unsigned Asel = (g & 2) ? v23 : v01;

    float2 acc2 = __half22float2(*(__half2*)&Asel);
    float2 slf2 = __half22float2(*(__half2*)&self_u);
    float2 res2 = __half22float2(*(__half2*)&res_u);
    int c0f = slice * 32 + f * 8 + g * 2;
    float2 scl = *(const float2*)(bnscale + c0f);
    float2 shf = *(const float2*)(bnshift + c0f);
    float r0 = fmaxf(fmaf((acc2.x + slf2.x) * iv, scl.x, shf.x), 0.f) + res2.x;
    float r1 = fmaxf(fmaf((acc2.y + slf2.y) * iv, scl.y, shf.y), 0.f) + res2.y;
    __half2 qo = __floats2half2_rn(r0, r1);
    __builtin_nontemporal_store(*(unsigned*)&qo, (unsigned*)&h16_w[eoff]);
}

// ---- pooling: one block per graph, vectorized 16B loads + 2-level reduce ---
__global__ __launch_bounds__(256) void k_pool(const ushort* __restrict__ h16,
                                              const int* __restrict__ batch,
                                              ushort* __restrict__ gp16) {
    int g = blockIdx.x;
    __shared__ int s_lo, s_hi;
    __shared__ float sm_sum[4][256];
    __shared__ float sm_max[4][256];
    if (threadIdx.x == 0) {
        int lo = 0, hi = N_NODES;
        while (lo < hi) { int m = (lo + hi) >> 1; if (batch[m] < g) lo = m + 1; else hi = m; }
        s_lo = lo;
        hi = N_NODES;
        while (lo < hi) { int m = (lo + hi) >> 1; if (batch[m] < g + 1) lo = m + 1; else hi = m; }
        s_hi = lo;
    }
    __syncthreads();
    int lo = s_lo, hi = s_hi;
    int t = threadIdx.x;
    int ng = t >> 5;              // node group 0..7
    int cg = t & 31;              // 8 cols starting cg*8
    const ushort* base = h16 + ((size_t)(cg >> 2) * NPAD) * 32 + (cg & 3) * 8;

    float s8[8], m8[8];
#pragma unroll
    for (int i = 0; i < 8; i++) { s8[i] = 0.f; m8[i] = -1e30f; }
    for (int n = lo + ng; n < hi; n += 8) {
        uint4 v = *(const uint4*)(base + (size_t)n * 32);
        const __half2* p = (const __half2*)&v;
#pragma unroll
        for (int i = 0; i < 4; i++) {
            float2 fv = __half22float2(p[i]);
            s8[2 * i]     += fv.x;
            s8[2 * i + 1] += fv.y;
            m8[2 * i]     = fmaxf(m8[2 * i], fv.x);
            m8[2 * i + 1] = fmaxf(m8[2 * i + 1], fv.y);
        }
    }
    // combine node-group pairs within the wave (lanes t, t^32)
#pragma unroll
    for (int i = 0; i < 8; i++) {
        s8[i] += __shfl_xor(s8[i], 32);
        m8[i] = fmaxf(m8[i], __shfl_xor(m8[i], 32));
    }
    int wv = t >> 6;
    if ((t & 32) == 0) {
#pragma unroll
        for (int i = 0; i < 8; i++) {
            sm_sum[wv][cg * 8 + i] = s8[i];
            sm_max[wv][cg * 8 + i] = m8[i];
        }
    }
    __syncthreads();
    float fs = sm_sum[0][t] + sm_sum[1][t] + sm_sum[2][t] + sm_sum[3][t];
    float fm = fmaxf(fmaxf(sm_max[0][t], sm_max[1][t]), fmaxf(sm_max[2][t], sm_max[3][t]));
    float cntf = fmaxf((float)(hi - lo), 1.0f);
    float mean = fs / cntf;
    float mxo = (hi > lo) ? fm : 0.0f;
    gp16[(size_t)g * 2 * HDIM + t] = __half_as_ushort(__float2half(mean));
    gp16[(size_t)g * 2 * HDIM + HDIM + t] = __half_as_ushort(__float2half(mxo));
}

// ---- head1 via MFMA: g1h = fp16(relu(gp16 @ W1 + b1)) ----------------------
__global__ __launch_bounds__(256) void k_head1_mfma(const ushort* __restrict__ A,
                                                    const _Float16* __restrict__ Bt,
                                                    const float* __restrict__ bias,
                                                    ushort* __restrict__ out16) {
    constexpr int K = 512, LDKH = 520;
    __shared__ _Float16 hs[64 * LDKH];
    int block_r = blockIdx.x * 64;
    for (int i = threadIdx.x; i < 64 * (K / 8); i += 256) {
        int row = i / (K / 8);
        int c = (i % (K / 8)) * 8;
        *(uint4*)&hs[row * LDKH + c] = *(const uint4*)(A + (size_t)(block_r + row) * K + c);
    }
    __syncthreads();

    int wave = threadIdx.x >> 6;
    int lane = threadIdx.x & 63;
    int l16 = lane & 15;
    int quad = lane >> 4;
    int n0 = wave * 64;

    f32x4 acc[4][4] = {};
    for (int k0 = 0; k0 < K; k0 += 32) {
        half8 a[4], b[4];
#pragma unroll
        for (int ai = 0; ai < 4; ai++)
            a[ai] = *(const half8*)&hs[(ai * 16 + l16) * LDKH + k0 + quad * 8];
#pragma unroll
        for (int bj = 0; bj < 4; bj++)
            b[bj] = *(const half8*)&Bt[(size_t)(n0 + bj * 16 + l16) * K + k0 + quad * 8];
#pragma unroll
        for (int ai = 0; ai < 4; ai++)
#pragma unroll
            for (int bj = 0; bj < 4; bj++)
                acc[ai][bj] = __builtin_amdgcn_mfma_f32_16x16x32_f16(a[ai], b[bj], acc[ai][bj], 0, 0, 0);
    }

#pragma unroll
    for (int ai = 0; ai < 4; ai++) {
        int rowb = block_r + ai * 16 + quad * 4;
#pragma unroll
        for (int r = 0; r < 4; r++) {
            int row = rowb + r;
#pragma unroll
            for (int bj = 0; bj < 4; bj++) {
                int col = n0 + bj * 16 + l16;
                float v = fmaxf(acc[ai][bj][r] + bias[col], 0.f);
                out16[(size_t)row * HDIM + col] = __half_as_ushort(__float2half(v));
            }
        }
    }
}

// ---- fused head2 + head3: block = 64 graphs, 128 threads -------------------
__global__ __launch_bounds__(128) void k_head23(const ushort* __restrict__ g1h,
                                                const _Float16* __restrict__ W2t,
                                                const float* __restrict__ b2,
                                                const float* __restrict__ W3,
                                                const float* __restrict__ b3,
                                                float* __restrict__ out) {
    __shared__ _Float16 hs[64 * 264];
    __shared__ float g2s[64 * 132];
    int block_r = blockIdx.x * 64;
    for (int i = threadIdx.x; i < 64 * 32; i += 128) {
        int row = i >> 5;
        int c = (i & 31) * 8;
        *(uint4*)&hs[row * 264 + c] = *(const uint4*)(g1h + (size_t)(block_r + row) * HDIM + c);
    }
    __syncthreads();

    int wave = threadIdx.x >> 6;
    int lane = threadIdx.x & 63;
    int l16 = lane & 15;
    int quad = lane >> 4;
    int n0 = wave * 64;

    f32x4 acc[4][4] = {};
    for (int k0 = 0; k0 < HDIM; k0 += 32) {
        half8 a[4], b[4];
#pragma unroll
        for (int ai = 0; ai < 4; ai++)
            a[ai] = *(const half8*)&hs[(ai * 16 + l16) * 264 + k0 + quad * 8];
#pragma unroll
        for (int bj = 0; bj < 4; bj++)
            b[bj] = *(const half8*)&W2t[(size_t)(n0 + bj * 16 + l16) * HDIM + k0 + quad * 8];
#pragma unroll
        for (int ai = 0; ai < 4; ai++)
#pragma unroll
            for (int bj = 0; bj < 4; bj++)
                acc[ai][bj] = __builtin_amdgcn_mfma_f32_16x16x32_f16(a[ai], b[bj], acc[ai][bj], 0, 0, 0);
    }
#pragma unroll
    for (int ai = 0; ai < 4; ai++) {
        int rowb = ai * 16 + quad * 4;
#pragma unroll
        for (int r = 0; r < 4; r++) {
            int row = rowb + r;
#pragma unroll
            for (int bj = 0; bj < 4; bj++) {
                int col = n0 + bj * 16 + l16;
                g2s[row * 132 + col] = fmaxf(acc[ai][bj][r] + b2[col], 0.f);
            }
        }
    }
    __syncthreads();

    // head3: 64 rows x 4 cols; thread -> (row, col pair)
    int r = threadIdx.x >> 1;
    int p = threadIdx.x & 1;
    float a0 = b3[2 * p], a1 = b3[2 * p + 1];
    for (int k = 0; k < 128; k++) {
        float v = g2s[r * 132 + k];
        a0 += v * W3[k * T_OUT + 2 * p];
        a1 += v * W3[k * T_OUT + 2 * p + 1];
    }
    out[(size_t)(block_r + r) * T_OUT + 2 * p] = a0;
    out[(size_t)(block_r + r) * T_OUT + 2 * p + 1] = a1;
}

extern "C" void kernel_launch(void* const* d_in, const int* in_sizes, int n_in,
                              void* d_out, int out_size, void* d_ws, size_t ws_size,
                              hipStream_t stream) {
    const float* x     = (const float*)d_in[0];
    const int*   ei    = (const int*)d_in[1];
    const int*   batch = (const int*)d_in[2];
    const float* projW = (const float*)d_in[3];
    const float* projb = (const float*)d_in[4];
    const float* convW = (const float*)d_in[5];
    const float* convb = (const float*)d_in[6];
    const float* gamma = (const float*)d_in[7];
    const float* beta  = (const float*)d_in[8];
    const float* mean  = (const float*)d_in[9];
    const float* var   = (const float*)d_in[10];
    const float* W1    = (const float*)d_in[11];
    const float* b1    = (const float*)d_in[12];
    const float* W2    = (const float*)d_in[13];
    const float* b2    = (const float*)d_in[14];
    const float* W3    = (const float*)d_in[15];
    const float* b3    = (const float*)d_in[16];
    float* out = (float*)d_out;

    // workspace layout (all segments 16B aligned)
    float*  wsf    = (float*)d_ws;
    float*  inv    = wsf;                        // NPAD f
    int*    cnt    = (int*)(wsf + NPAD);         // NPAD i
    int*    rowptr = cnt + NPAD;                 // NPAD i
    int*    wpos   = rowptr + NPAD;              // NPAD i
    int*    iscan  = wpos + NPAD;                // NPAD i
    int*    bsum   = iscan + NPAD;               // 256 i
    int*    boff   = bsum + 256;                 // 256 i (unused, kept for layout)
    ushort* csr    = (ushort*)(boff + 256);      // 800256 u16
    ushort* hWh    = csr + 800256;               // [8][NPAD][32] fp16 messages (slice-major)
    ushort* h16    = hWh + (size_t)NPAD * 256;   // [8][NPAD][32] fp16 residual (slice-major)
    ushort* gp16   = h16 + (size_t)NPAD * 256;   // G*512 fp16
    ushort* g1h    = gp16 + (size_t)G_GRAPHS * 512;           // G*256 fp16
    _Float16* Wt   = (_Float16*)(g1h + (size_t)G_GRAPHS * HDIM); // WT_TOT fp16
    float*  bnp    = (float*)(Wt + WT_TOT);                   // 2*L*H f (scale | shift)

    // ---- CSR build + weight transposes + BN precompute + zero rows ----
    hipMemsetAsync(cnt, 0, NPAD * sizeof(int), stream);
    k_deg_wcvt<<<(E_EDGES + 255) / 256, 256, 0, stream>>>(ei + E_EDGES, cnt,
                                                          convW, projW, W1, W2, Wt,
                                                          convb, gamma, beta, mean, var, bnp,
                                                          hWh);
    k_scan1<<<NBLK, 256, 0, stream>>>(cnt, iscan, bsum);
    k_scan23<<<NBLK, 256, 0, stream>>>(cnt, iscan, bsum, rowptr, wpos, inv);
    k_scatter<<<(E_EDGES + 255) / 256, 256, 0, stream>>>(ei, wpos, csr);

    // ---- proj (MFMA) ----
    k_proj_mfma<<<(N_NODES + 63) / 64, 256, 0, stream>>>(x, Wt + WT_PROJ, projb, h16, N_NODES);

    // ---- GCN layers ----
    int gemm_blocks = (N_NODES + 127) / 128;
    for (int l = 0; l < L_LAYERS; l++) {
        k_gemm_mfma<<<gemm_blocks, 512, 0, stream>>>(h16, Wt + WT_CONV + (size_t)l * HDIM * HDIM,
                                                     inv, (_Float16*)hWh, N_NODES);
        k_aggr<<<(N_NODES / 16) * SLICES, 256, 0, stream>>>(rowptr, csr, hWh, inv,
                                                            bnp + l * HDIM,
                                                            bnp + L_LAYERS * HDIM + l * HDIM, h16);
    }

    // ---- pool + head ----
    k_pool<<<G_GRAPHS, HDIM, 0, stream>>>(h16, batch, gp16);
    k_head1_mfma<<<G_GRAPHS / 64, 256, 0, stream>>>(gp16, Wt + WT_H1, b1, g1h);
    k_head23<<<G_GRAPHS / 64, 128, 0, stream>>>(g1h, Wt + WT_H2, b2, W3, b3, out);
}

// Round 9
// 509.639 us; speedup vs baseline: 1.1439x; 1.0385x over previous
//
#include <hip/hip_runtime.h>
#include <hip/hip_bf16.h>
#include <hip/hip_fp16.h>

#define N_NODES 50000
#define F_IN    64
#define HDIM    256
#define E_EDGES 800000
#define G_GRAPHS 2048
#define L_LAYERS 4
#define T_OUT   4
#define BN_EPS  1e-5f

#define NPAD    50176   // 196 * 256
#define NBLK    196
#define LDK     264     // fp16 LDS row stride for K=256 tiles
#define SLICES  4       // feature slices; 64 fp16 = 128B each (one transaction per edge-gather)

// Wt buffer offsets (fp16 elements)
#define WT_CONV 0
#define WT_PROJ 262144
#define WT_H1   278528
#define WT_H2   409600
#define WT_TOT  442368

typedef _Float16 half8 __attribute__((ext_vector_type(8)));
typedef float    f32x4 __attribute__((ext_vector_type(4)));
typedef unsigned int u32x4 __attribute__((ext_vector_type(4)));

// ---- degree count + weight transposes + BN precompute + zero rows ----------
__global__ void k_deg_wcvt(const int* __restrict__ dst, int* __restrict__ cnt,
                           const float* __restrict__ convW, const float* __restrict__ projW,
                           const float* __restrict__ W1, const float* __restrict__ W2,
                           _Float16* __restrict__ Wt,
                           const float* __restrict__ convb, const float* __restrict__ gamma,
                           const float* __restrict__ beta, const float* __restrict__ mean,
                           const float* __restrict__ var, float* __restrict__ bnp,
                           ushort* __restrict__ Wh) {
    int i = blockIdx.x * 256 + threadIdx.x;
    if (i < E_EDGES) atomicAdd(&cnt[dst[i]], 1);
    if (i < 262144) {                       // conv: 4 x [256x256]
        int l = i >> 16, r = i & 65535;
        int k = r >> 8, n = r & 255;
        Wt[WT_CONV + (size_t)l * 65536 + n * 256 + k] = (_Float16)convW[(size_t)l * 65536 + k * 256 + n];
        return;
    }
    int j = i - 262144;
    if (j >= 0 && j < 16384) {              // proj: [64x256] -> [256][64]
        int k = j >> 8, n = j & 255;
        Wt[WT_PROJ + n * 64 + k] = (_Float16)projW[k * 256 + n];
        return;
    }
    j -= 16384;
    if (j >= 0 && j < 131072) {             // W1: [512x256] -> [256][512]
        int k = j >> 8, n = j & 255;
        Wt[WT_H1 + n * 512 + k] = (_Float16)W1[k * 256 + n];
        return;
    }
    j -= 131072;
    if (j >= 0 && j < 32768) {              // W2: [256x128] -> [128][256]
        int k = j >> 7, n = j & 127;
        Wt[WT_H2 + n * 256 + k] = (_Float16)W2[k * 128 + n];
        return;
    }
    j -= 32768;
    if (j >= 0 && j < L_LAYERS * HDIM) {    // BN: scale = g*rsqrt(v+eps), shift = (cb-m)*scale+b
        float scv = gamma[j] * rsqrtf(var[j] + BN_EPS);
        bnp[j] = scv;
        bnp[L_LAYERS * HDIM + j] = (convb[j] - mean[j]) * scv + beta[j];
        return;
    }
    j -= L_LAYERS * HDIM;
    if (j >= 0 && j < SLICES * 64) {        // zero row (idx N_NODES) in each 128B slice
        int sl = j >> 6, w = j & 63;
        Wh[((size_t)sl * NPAD + N_NODES) * 64 + w] = 0;
    }
}

// ---- scan pass 1: per-block inclusive scan ---------------------------------
__global__ void k_scan1(const int* __restrict__ cnt, int* __restrict__ iscan,
                        int* __restrict__ bsum) {
    __shared__ int sm[256];
    int t = threadIdx.x, i = blockIdx.x * 256 + t;
    sm[t] = cnt[i];
    __syncthreads();
    for (int off = 1; off < 256; off <<= 1) {
        int u = (t >= off) ? sm[t - off] : 0;
        __syncthreads();
        sm[t] += u;
        __syncthreads();
    }
    iscan[i] = sm[t];
    if (t == 255) bsum[blockIdx.x] = sm[255];
}

// ---- scan pass 2: block offset computed locally + emit rowptr/wpos/inv -----
__global__ void k_scan23(const int* __restrict__ cnt, const int* __restrict__ iscan,
                         const int* __restrict__ bsum, int* __restrict__ rowptr,
                         int* __restrict__ wpos, float* __restrict__ inv) {
    __shared__ int sm[256];
    int t = threadIdx.x;
    int b = blockIdx.x;
    sm[t] = (t < b) ? bsum[t] : 0;   // t < b <= 195 < NBLK
    __syncthreads();
    for (int off = 128; off > 0; off >>= 1) {
        if (t < off) sm[t] += sm[t + off];
        __syncthreads();
    }
    int boff = sm[0];
    int i = b * 256 + t;
    int c = cnt[i];
    int excl = boff + iscan[i] - c;
    rowptr[i] = excl;
    wpos[i] = excl;
    inv[i] = rsqrtf((float)c + 1.0f);
}

// ---- scatter edges into CSR order (src ids fit in ushort: N < 65536) -------
__global__ void k_scatter(const int* __restrict__ ei, int* __restrict__ wpos,
                          ushort* __restrict__ csr_src) {
    int e = blockIdx.x * blockDim.x + threadIdx.x;
    if (e < E_EDGES) {
        int s = ei[e];
        int d = ei[E_EDGES + e];
        int pos = atomicAdd(&wpos[d], 1);
        csr_src[pos] = (ushort)s;
    }
}

// ---- proj GEMM via MFMA: h16 = fp16(relu(x @ Wp + b)), slice-major out -----
__global__ __launch_bounds__(256) void k_proj_mfma(const float* __restrict__ x,
                                                   const _Float16* __restrict__ Wpt,
                                                   const float* __restrict__ bias,
                                                   ushort* __restrict__ h16, int nrows) {
    __shared__ _Float16 hs[64 * 264];     // A staged at stride 72; output tile at stride 264
    int block_r = blockIdx.x * 64;
    for (int i = threadIdx.x; i < 64 * 16; i += 256) {
        int row = i >> 4;
        int c4 = (i & 15) * 4;
        float4 v = (block_r + row < nrows)
                       ? *(const float4*)(x + (size_t)(block_r + row) * F_IN + c4)
                       : make_float4(0.f, 0.f, 0.f, 0.f);
        _Float16* p = &hs[row * 72 + c4];
        p[0] = (_Float16)v.x; p[1] = (_Float16)v.y;
        p[2] = (_Float16)v.z; p[3] = (_Float16)v.w;
    }
    __syncthreads();

    int wave = threadIdx.x >> 6;
    int lane = threadIdx.x & 63;
    int l16 = lane & 15;
    int quad = lane >> 4;
    int n0 = wave * 64;

    f32x4 acc[4][4] = {};
#pragma unroll
    for (int k0 = 0; k0 < F_IN; k0 += 32) {
        half8 a[4], b[4];
#pragma unroll
        for (int ai = 0; ai < 4; ai++)
            a[ai] = *(const half8*)&hs[(ai * 16 + l16) * 72 + k0 + quad * 8];
#pragma unroll
        for (int bj = 0; bj < 4; bj++)
            b[bj] = *(const half8*)&Wpt[(size_t)(n0 + bj * 16 + l16) * F_IN + k0 + quad * 8];
#pragma unroll
        for (int ai = 0; ai < 4; ai++)
#pragma unroll
            for (int bj = 0; bj < 4; bj++)
                acc[ai][bj] = __builtin_amdgcn_mfma_f32_16x16x32_f16(a[ai], b[bj], acc[ai][bj], 0, 0, 0);
    }
    __syncthreads();          // all waves done reading A before overwrite

#pragma unroll
    for (int ai = 0; ai < 4; ai++) {
#pragma unroll
        for (int r = 0; r < 4; r++) {
            int lrow = ai * 16 + quad * 4 + r;
#pragma unroll
            for (int bj = 0; bj < 4; bj++) {
                int col = n0 + bj * 16 + l16;
                float v = fmaxf(acc[ai][bj][r] + bias[col], 0.f);
                hs[lrow * 264 + col] = (_Float16)v;
            }
        }
    }
    __syncthreads();

    for (int i = threadIdx.x; i < 2048; i += 256) {   // 4 slices x 64 rows x 8 granules
        int s = i >> 9;
        int j = i & 511;
        int lrow = j >> 3;
        int q = j & 7;
        if (block_r + lrow < nrows)
            *(uint4*)(h16 + ((size_t)s * NPAD + block_r + lrow) * 64 + q * 8) =
                *(const uint4*)&hs[lrow * 264 + s * 64 + q * 8];
    }
}

// ---- conv GEMM via MFMA: 128x256 tile, slice-major in/out ------------------
__global__ __launch_bounds__(512) void k_gemm_mfma(const ushort* __restrict__ h16,
                                                   const _Float16* __restrict__ Wt,
                                                   const float* __restrict__ inv,
                                                   _Float16* __restrict__ outh, int nrows) {
    __shared__ _Float16 hs[128 * LDK];    // 67.6 KB
    int block_r = blockIdx.x * 128;
    for (int i = threadIdx.x; i < 128 * 32; i += 512) {
        int row = i >> 5;
        int q = i & 31;             // slice = q>>3, 16B granule = q&7
        uint4 v;
        if (block_r + row < nrows)
            v = *(const uint4*)(h16 + ((size_t)(q >> 3) * NPAD + block_r + row) * 64 + (q & 7) * 8);
        else
            v = make_uint4(0u, 0u, 0u, 0u);
        *(uint4*)&hs[row * LDK + q * 8] = v;
    }
    __syncthreads();

    int wave = threadIdx.x >> 6;    // 0..7
    int wr = wave >> 2;             // row group 0..1
    int wc = wave & 3;              // col group 0..3
    int lane = threadIdx.x & 63;
    int l16 = lane & 15;
    int quad = lane >> 4;
    int n0 = wc * 64;
    int r0 = wr * 64;

    f32x4 acc[4][4] = {};
    for (int k0 = 0; k0 < HDIM; k0 += 32) {
        half8 a[4], b[4];
#pragma unroll
        for (int ai = 0; ai < 4; ai++)
            a[ai] = *(const half8*)&hs[(r0 + ai * 16 + l16) * LDK + k0 + quad * 8];
#pragma unroll
        for (int bj = 0; bj < 4; bj++)
            b[bj] = *(const half8*)&Wt[(size_t)(n0 + bj * 16 + l16) * HDIM + k0 + quad * 8];
#pragma unroll
        for (int ai = 0; ai < 4; ai++)
#pragma unroll
            for (int bj = 0; bj < 4; bj++)
                acc[ai][bj] = __builtin_amdgcn_mfma_f32_16x16x32_f16(a[ai], b[bj], acc[ai][bj], 0, 0, 0);
    }
    __syncthreads();

#pragma unroll
    for (int ai = 0; ai < 4; ai++) {
#pragma unroll
        for (int r = 0; r < 4; r++) {
            int lrow = r0 + ai * 16 + quad * 4 + r;
            float sc = inv[block_r + lrow];      // inv is NPAD-sized: phantom rows safe
#pragma unroll
            for (int bj = 0; bj < 4; bj++) {
                int col = n0 + bj * 16 + l16;
                hs[lrow * LDK + col] = (_Float16)(acc[ai][bj][r] * sc);
            }
        }
    }
    __syncthreads();

    for (int i = threadIdx.x; i < 4096; i += 512) {   // 4 slices x 128 rows x 8 granules
        int s = i >> 10;
        int j = i & 1023;
        int lrow = j >> 3;
        int q = j & 7;
        if (block_r + lrow < nrows)
            *(uint4*)((ushort*)outh + ((size_t)s * NPAD + block_r + lrow) * 64 + q * 8) =
                *(const uint4*)&hs[lrow * LDK + s * 64 + q * 8];
    }
}

// ---- fused CSR aggregation, 128B-slice gathers across XCDs -----------------
// blockIdx % 4 = slice (128B of the 512B row); consecutive blocks round-robin
// XCDs so each XCD touches ONE slice (6.4MB working set, partial L2 + L3).
// Wave = 2 nodes x 4 edge-slots x 8 granules: each edge gather is ONE 128B
// contiguous request (8 lanes x 16B) -> half the transaction count of 64B
// slicing. Transaction-throughput wall theory from r6/r8.
__global__ __launch_bounds__(256) void k_aggr(const int* __restrict__ rowptr,
                                              const ushort* __restrict__ csr,
                                              const ushort* __restrict__ hWh,
                                              const float* __restrict__ inv,
                                              const float* __restrict__ bnscale,
                                              const float* __restrict__ bnshift,
                                              ushort* __restrict__ h16) {
    int slice = blockIdx.x & 3;
    int chunk = blockIdx.x >> 2;
    int lane = threadIdx.x & 63;
    int wv = threadIdx.x >> 6;
    int nb = lane >> 5;            // node sub 0..1
    int g  = (lane >> 3) & 3;      // edge slot / half2-pair 0..3
    int f  = lane & 7;             // 16B granule 0..7
    int l31 = lane & 31;
    int node = chunk * 8 + wv * 2 + nb;    // grid covers exactly N_NODES

    const uint4* tbl = (const uint4*)hWh + (size_t)slice * (NPAD * 8);
    const unsigned* tbl_w = (const unsigned*)tbl;
    const unsigned* h16_w = (const unsigned*)h16 + (size_t)slice * (NPAD * 32);

    int beg = rowptr[node], end = rowptr[node + 1];
    int m = end - beg;

    // preload up to 64 edge indices per node (cached; csr reused across layers)
    int idx0 = (l31      < m) ? (int)csr[beg + l31     ] : N_NODES;
    int idx1 = (l31 + 32 < m) ? (int)csr[beg + l31 + 32] : N_NODES;

    // per-lane 4B self (table) + residual (single-use -> NT), issued early
    unsigned eoff = (unsigned)node * 32u + (unsigned)(f * 4 + g);   // dword idx
    unsigned self_u = tbl_w[eoff];
    unsigned res_u  = __builtin_nontemporal_load(&h16_w[eoff]);
    float iv = inv[node];

    // wave-uniform chunk count over the 2 nodes (pad -> zero row)
    int mm = m;
    mm = max(mm, __shfl_xor(mm, 32));

    __half2 a0 = __floats2half2_rn(0.f, 0.f), a1 = a0, a2 = a0, a3 = a0;

#define AGGR_CHUNK(IDX, BASE)                                               \
    {                                                                       \
        _Pragma("unroll")                                                   \
        for (int jj = 0; jj < 16; jj += 4) {                                \
            int s = __shfl((IDX), (lane & 32) | ((BASE) + jj + g));         \
            uint4 u = tbl[s * 8 + f];                                       \
            const __half2* p = (const __half2*)&u;                          \
            a0 = __hadd2(a0, p[0]);                                         \
            a1 = __hadd2(a1, p[1]);                                         \
            a2 = __hadd2(a2, p[2]);                                         \
            a3 = __hadd2(a3, p[3]);                                         \
        }                                                                   \
    }

    AGGR_CHUNK(idx0, 0);
    if (mm > 16) AGGR_CHUNK(idx0, 16);
    if (mm > 32) AGGR_CHUNK(idx1, 0);
    if (mm > 48) AGGR_CHUNK(idx1, 16);
    // safety tail for degree > 64 (essentially never for Poisson(16))
    for (int eo = 64; eo < mm; eo += 32) {
        int e = eo + l31;
        int idxT = (e < m) ? (int)csr[beg + e] : N_NODES;
        AGGR_CHUNK(idxT, 0);
        if (mm > eo + 16) AGGR_CHUNK(idxT, 16);
    }
#undef AGGR_CHUNK

    // reduce across the 4 edge slots (lane bits 3,4); full sum in all lanes
    __half2 accv[4] = {a0, a1, a2, a3};
#pragma unroll
    for (int i = 0; i < 4; i++) {
        unsigned pk = *(unsigned*)&accv[i];
        int q = __shfl_xor((int)pk, 8);
        accv[i] = __hadd2(accv[i], *(__half2*)&q);
        pk = *(unsigned*)&accv[i];
        q = __shfl_xor((int)pk, 16);
        accv[i] = __hadd2(accv[i], *(__half2*)&q);
    }

    // lane (g,f) finishes half2-pair g of granule f (3 cndmask selects)
    unsigned A0 = *(unsigned*)&accv[0], A1 = *(unsigned*)&accv[1];
    unsigned A2 = *(unsigned*)&accv[2], A3 = *(unsigned*)&accv[3];
    unsigned v01 = (g & 1) ? A1 : A0;
    unsigned v23 = (g & 1) ? A3 : A2;
    unsigned Asel = (g & 2) ? v23 : v01;

    float2 acc2 = __half22float2(*(__half2*)&Asel);
    float2 slf2 = __half22float2(*(__half2*)&self_u);
    float2 res2 = __half22float2(*(__half2*)&res_u);
    int c0f = slice * 64 + f * 8 + g * 2;
    float2 scl = *(const float2*)(bnscale + c0f);
    float2 shf = *(const float2*)(bnshift + c0f);
    float r0 = fmaxf(fmaf((acc2.x + slf2.x) * iv, scl.x, shf.x), 0.f) + res2.x;
    float r1 = fmaxf(fmaf((acc2.y + slf2.y) * iv, scl.y, shf.y), 0.f) + res2.y;
    __half2 qo = __floats2half2_rn(r0, r1);
    __builtin_nontemporal_store(*(unsigned*)&qo, (unsigned*)&h16_w[eoff]);
}

// ---- pooling: one block per graph, vectorized 16B loads + 2-level reduce ---
__global__ __launch_bounds__(256) void k_pool(const ushort* __restrict__ h16,
                                              const int* __restrict__ batch,
                                              ushort* __restrict__ gp16) {
    int g = blockIdx.x;
    __shared__ int s_lo, s_hi;
    __shared__ float sm_sum[4][256];
    __shared__ float sm_max[4][256];
    if (threadIdx.x == 0) {
        int lo = 0, hi = N_NODES;
        while (lo < hi) { int m = (lo + hi) >> 1; if (batch[m] < g) lo = m + 1; else hi = m; }
        s_lo = lo;
        hi = N_NODES;
        while (lo < hi) { int m = (lo + hi) >> 1; if (batch[m] < g + 1) lo = m + 1; else hi = m; }
        s_hi = lo;
    }
    __syncthreads();
    int lo = s_lo, hi = s_hi;
    int t = threadIdx.x;
    int ng = t >> 5;              // node group 0..7
    int cg = t & 31;              // 8 cols starting cg*8
    const ushort* base = h16 + ((size_t)(cg >> 3) * NPAD) * 64 + (cg & 7) * 8;

    float s8[8], m8[8];
#pragma unroll
    for (int i = 0; i < 8; i++) { s8[i] = 0.f; m8[i] = -1e30f; }
    for (int n = lo + ng; n < hi; n += 8) {
        uint4 v = *(const uint4*)(base + (size_t)n * 64);
        const __half2* p = (const __half2*)&v;
#pragma unroll
        for (int i = 0; i < 4; i++) {
            float2 fv = __half22float2(p[i]);
            s8[2 * i]     += fv.x;
            s8[2 * i + 1] += fv.y;
            m8[2 * i]     = fmaxf(m8[2 * i], fv.x);
            m8[2 * i + 1] = fmaxf(m8[2 * i + 1], fv.y);
        }
    }
    // combine node-group pairs within the wave (lanes t, t^32)
#pragma unroll
    for (int i = 0; i < 8; i++) {
        s8[i] += __shfl_xor(s8[i], 32);
        m8[i] = fmaxf(m8[i], __shfl_xor(m8[i], 32));
    }
    int wv = t >> 6;
    if ((t & 32) == 0) {
#pragma unroll
        for (int i = 0; i < 8; i++) {
            sm_sum[wv][cg * 8 + i] = s8[i];
            sm_max[wv][cg * 8 + i] = m8[i];
        }
    }
    __syncthreads();
    float fs = sm_sum[0][t] + sm_sum[1][t] + sm_sum[2][t] + sm_sum[3][t];
    float fm = fmaxf(fmaxf(sm_max[0][t], sm_max[1][t]), fmaxf(sm_max[2][t], sm_max[3][t]));
    float cntf = fmaxf((float)(hi - lo), 1.0f);
    float mean = fs / cntf;
    float mxo = (hi > lo) ? fm : 0.0f;
    gp16[(size_t)g * 2 * HDIM + t] = __half_as_ushort(__float2half(mean));
    gp16[(size_t)g * 2 * HDIM + HDIM + t] = __half_as_ushort(__float2half(mxo));
}

// ---- head1 via MFMA: g1h = fp16(relu(gp16 @ W1 + b1)) ----------------------
__global__ __launch_bounds__(256) void k_head1_mfma(const ushort* __restrict__ A,
                                                    const _Float16* __restrict__ Bt,
                                                    const float* __restrict__ bias,
                                                    ushort* __restrict__ out16) {
    constexpr int K = 512, LDKH = 520;
    __shared__ _Float16 hs[64 * LDKH];
    int block_r = blockIdx.x * 64;
    for (int i = threadIdx.x; i < 64 * (K / 8); i += 256) {
        int row = i / (K / 8);
        int c = (i % (K / 8)) * 8;
        *(uint4*)&hs[row * LDKH + c] = *(const uint4*)(A + (size_t)(block_r + row) * K + c);
    }
    __syncthreads();

    int wave = threadIdx.x >> 6;
    int lane = threadIdx.x & 63;
    int l16 = lane & 15;
    int quad = lane >> 4;
    int n0 = wave * 64;

    f32x4 acc[4][4] = {};
    for (int k0 = 0; k0 < K; k0 += 32) {
        half8 a[4], b[4];
#pragma unroll
        for (int ai = 0; ai < 4; ai++)
            a[ai] = *(const half8*)&hs[(ai * 16 + l16) * LDKH + k0 + quad * 8];
#pragma unroll
        for (int bj = 0; bj < 4; bj++)
            b[bj] = *(const half8*)&Bt[(size_t)(n0 + bj * 16 + l16) * K + k0 + quad * 8];
#pragma unroll
        for (int ai = 0; ai < 4; ai++)
#pragma unroll
            for (int bj = 0; bj < 4; bj++)
                acc[ai][bj] = __builtin_amdgcn_mfma_f32_16x16x32_f16(a[ai], b[bj], acc[ai][bj], 0, 0, 0);
    }

#pragma unroll
    for (int ai = 0; ai < 4; ai++) {
        int rowb = block_r + ai * 16 + quad * 4;
#pragma unroll
        for (int r = 0; r < 4; r++) {
            int row = rowb + r;
#pragma unroll
            for (int bj = 0; bj < 4; bj++) {
                int col = n0 + bj * 16 + l16;
                float v = fmaxf(acc[ai][bj][r] + bias[col], 0.f);
                out16[(size_t)row * HDIM + col] = __half_as_ushort(__float2half(v));
            }
        }
    }
}

// ---- fused head2 + head3: block = 64 graphs, 128 threads -------------------
__global__ __launch_bounds__(128) void k_head23(const ushort* __restrict__ g1h,
                                                const _Float16* __restrict__ W2t,
                                                const float* __restrict__ b2,
                                                const float* __restrict__ W3,
                                                const float* __restrict__ b3,
                                                float* __restrict__ out) {
    __shared__ _Float16 hs[64 * 264];
    __shared__ float g2s[64 * 132];
    int block_r = blockIdx.x * 64;
    for (int i = threadIdx.x; i < 64 * 32; i += 128) {
        int row = i >> 5;
        int c = (i & 31) * 8;
        *(uint4*)&hs[row * 264 + c] = *(const uint4*)(g1h + (size_t)(block_r + row) * HDIM + c);
    }
    __syncthreads();

    int wave = threadIdx.x >> 6;
    int lane = threadIdx.x & 63;
    int l16 = lane & 15;
    int quad = lane >> 4;
    int n0 = wave * 64;

    f32x4 acc[4][4] = {};
    for (int k0 = 0; k0 < HDIM; k0 += 32) {
        half8 a[4], b[4];
#pragma unroll
        for (int ai = 0; ai < 4; ai++)
            a[ai] = *(const half8*)&hs[(ai * 16 + l16) * 264 + k0 + quad * 8];
#pragma unroll
        for (int bj = 0; bj < 4; bj++)
            b[bj] = *(const half8*)&W2t[(size_t)(n0 + bj * 16 + l16) * HDIM + k0 + quad * 8];
#pragma unroll
        for (int ai = 0; ai < 4; ai++)
#pragma unroll
            for (int bj = 0; bj < 4; bj++)
                acc[ai][bj] = __builtin_amdgcn_mfma_f32_16x16x32_f16(a[ai], b[bj], acc[ai][bj], 0, 0, 0);
    }
#pragma unroll
    for (int ai = 0; ai < 4; ai++) {
        int rowb = ai * 16 + quad * 4;
#pragma unroll
        for (int r = 0; r < 4; r++) {
            int row = rowb + r;
#pragma unroll
            for (int bj = 0; bj < 4; bj++) {
                int col = n0 + bj * 16 + l16;
                g2s[row * 132 + col] = fmaxf(acc[ai][bj][r] + b2[col], 0.f);
            }
        }
    }
    __syncthreads();

    // head3: 64 rows x 4 cols; thread -> (row, col pair)
    int r = threadIdx.x >> 1;
    int p = threadIdx.x & 1;
    float a0 = b3[2 * p], a1 = b3[2 * p + 1];
    for (int k = 0; k < 128; k++) {
        float v = g2s[r * 132 + k];
        a0 += v * W3[k * T_OUT + 2 * p];
        a1 += v * W3[k * T_OUT + 2 * p + 1];
    }
    out[(size_t)(block_r + r) * T_OUT + 2 * p] = a0;
    out[(size_t)(block_r + r) * T_OUT + 2 * p + 1] = a1;
}

extern "C" void kernel_launch(void* const* d_in, const int* in_sizes, int n_in,
                              void* d_out, int out_size, void* d_ws, size_t ws_size,
                              hipStream_t stream) {
    const float* x     = (const float*)d_in[0];
    const int*   ei    = (const int*)d_in[1];
    const int*   batch = (const int*)d_in[2];
    const float* projW = (const float*)d_in[3];
    const float* projb = (const float*)d_in[4];
    const float* convW = (const float*)d_in[5];
    const float* convb = (const float*)d_in[6];
    const float* gamma = (const float*)d_in[7];
    const float* beta  = (const float*)d_in[8];
    const float* mean  = (const float*)d_in[9];
    const float* var   = (const float*)d_in[10];
    const float* W1    = (const float*)d_in[11];
    const float* b1    = (const float*)d_in[12];
    const float* W2    = (const float*)d_in[13];
    const float* b2    = (const float*)d_in[14];
    const float* W3    = (const float*)d_in[15];
    const float* b3    = (const float*)d_in[16];
    float* out = (float*)d_out;

    // workspace layout (all segments 16B aligned)
    float*  wsf    = (float*)d_ws;
    float*  inv    = wsf;                        // NPAD f
    int*    cnt    = (int*)(wsf + NPAD);         // NPAD i
    int*    rowptr = cnt + NPAD;                 // NPAD i
    int*    wpos   = rowptr + NPAD;              // NPAD i
    int*    iscan  = wpos + NPAD;                // NPAD i
    int*    bsum   = iscan + NPAD;               // 256 i
    int*    boff   = bsum + 256;                 // 256 i (unused, kept for layout)
    ushort* csr    = (ushort*)(boff + 256);      // 800256 u16
    ushort* hWh    = csr + 800256;               // [4][NPAD][64] fp16 messages (slice-major)
    ushort* h16    = hWh + (size_t)NPAD * 256;   // [4][NPAD][64] fp16 residual (slice-major)
    ushort* gp16   = h16 + (size_t)NPAD * 256;   // G*512 fp16
    ushort* g1h    = gp16 + (size_t)G_GRAPHS * 512;           // G*256 fp16
    _Float16* Wt   = (_Float16*)(g1h + (size_t)G_GRAPHS * HDIM); // WT_TOT fp16
    float*  bnp    = (float*)(Wt + WT_TOT);                   // 2*L*H f (scale | shift)

    // ---- CSR build + weight transposes + BN precompute + zero rows ----
    hipMemsetAsync(cnt, 0, NPAD * sizeof(int), stream);
    k_deg_wcvt<<<(E_EDGES + 255) / 256, 256, 0, stream>>>(ei + E_EDGES, cnt,
                                                          convW, projW, W1, W2, Wt,
                                                          convb, gamma, beta, mean, var, bnp,
                                                          hWh);
    k_scan1<<<NBLK, 256, 0, stream>>>(cnt, iscan, bsum);
    k_scan23<<<NBLK, 256, 0, stream>>>(cnt, iscan, bsum, rowptr, wpos, inv);
    k_scatter<<<(E_EDGES + 255) / 256, 256, 0, stream>>>(ei, wpos, csr);

    // ---- proj (MFMA) ----
    k_proj_mfma<<<(N_NODES + 63) / 64, 256, 0, stream>>>(x, Wt + WT_PROJ, projb, h16, N_NODES);

    // ---- GCN layers ----
    int gemm_blocks = (N_NODES + 127) / 128;
    for (int l = 0; l < L_LAYERS; l++) {
        k_gemm_mfma<<<gemm_blocks, 512, 0, stream>>>(h16, Wt + WT_CONV + (size_t)l * HDIM * HDIM,
                                                     inv, (_Float16*)hWh, N_NODES);
        k_aggr<<<(N_NODES / 8) * SLICES, 256, 0, stream>>>(rowptr, csr, hWh, inv,
                                                           bnp + l * HDIM,
                                                           bnp + L_LAYERS * HDIM + l * HDIM, h16);
    }

    // ---- pool + head ----
    k_pool<<<G_GRAPHS, HDIM, 0, stream>>>(h16, batch, gp16);
    k_head1_mfma<<<G_GRAPHS / 64, 256, 0, stream>>>(gp16, Wt + WT_H1, b1, g1h);
    k_head23<<<G_GRAPHS / 64, 128, 0, stream>>>(g1h, Wt + WT_H2, b2, W3, b3, out);
}